// Round 12
// baseline (4049.941 us; speedup 1.0000x reference)
//
#include <hip/hip_runtime.h>
#include <stdint.h>

// R15 = R14 (best: 3968us steady) + DEDICATED pre-spinning barrier master.
//  Last untested sync coupling: the barrier master (WG0) was also a worker —
//  every release chain was [master's stage work] -> [scan] -> [fan-out].
//  Now: 129 WGs. WGs 0..127 = workers (R14 bodies unchanged, g<128 guards).
//  WG 128 = pure master: 128 threads tight-spin one arrive line each DURING
//  the stage (observation within ~1 LLC RT of last arrival), then fan out the
//  128 per-WG release lines; winner barrier: master reduces KEY[] itself and
//  fans out (ep<<14)|token. Worker barrier = arrive store + poll own line.
//  Prelude barriers: WG0-master over 129 arrivals (3 uses, unchanged proto).
//  Epochs: 3 prelude + 4/iter, master counts identically. Stale-value safety
//  identical to R14 (monotone, != / payload-epoch compares).

#define NWG 129
#define NWRK 128
#define NT 256

typedef unsigned long long ull;

__device__ __forceinline__ float ld_c(const float* p){
  return __hip_atomic_load(p, __ATOMIC_RELAXED, __HIP_MEMORY_SCOPE_AGENT);
}
__device__ __forceinline__ void st_c(float* p, float v){
  __hip_atomic_store(p, v, __ATOMIC_RELAXED, __HIP_MEMORY_SCOPE_AGENT);
}
__device__ __forceinline__ int ld_fi(const int* p){
  return __hip_atomic_load(p, __ATOMIC_RELAXED, __HIP_MEMORY_SCOPE_AGENT);
}
__device__ __forceinline__ void st_fi(int* p, int v){
  __hip_atomic_store(p, v, __ATOMIC_RELAXED, __HIP_MEMORY_SCOPE_AGENT);
}
__device__ __forceinline__ ull ld_u64(const ull* p){
  return __hip_atomic_load(p, __ATOMIC_RELAXED, __HIP_MEMORY_SCOPE_AGENT);
}
__device__ __forceinline__ void st_u64(ull* p, ull v){
  __hip_atomic_store(p, v, __ATOMIC_RELAXED, __HIP_MEMORY_SCOPE_AGENT);
}

__device__ __forceinline__ float wredsum(float v){
#pragma unroll
  for (int m=32;m;m>>=1) v += __shfl_xor(v,m,64);
  return v;
}
__device__ __forceinline__ float wredmax(float v){
#pragma unroll
  for (int m=32;m;m>>=1) v = fmaxf(v,__shfl_xor(v,m,64));
  return v;
}
__device__ __forceinline__ float g32sum(float v){
#pragma unroll
  for (int m=16;m;m>>=1) v += __shfl_xor(v,m,64);
  return v;
}
__device__ __forceinline__ float g32max(float v){
#pragma unroll
  for (int m=16;m;m>>=1) v = fmaxf(v,__shfl_xor(v,m,64));
  return v;
}
__device__ __forceinline__ ull shflx64(ull v,int m){
  unsigned int lo=(unsigned int)(v&0xffffffffull), hi=(unsigned int)(v>>32);
  lo=__shfl_xor(lo,m,64); hi=__shfl_xor(hi,m,64);
  return (((ull)hi)<<32)|(ull)lo;
}

__device__ __forceinline__ float pe_val(int l, int e){
  int j = e >> 1;
  float dv = expf((float)(2*j) * (-0.035977892078031970f));
  float arg = (float)l * dv;
  return (e & 1) ? cosf(arg) : sinf(arg);
}

// A-chain: cross blocks x2 (rank-1 collapsed) + LN -> rrow. WG-uniform.
__device__ __forceinline__ void a_chain(const float* xrow, float* rrow,
    float* m8, float* redv,
    const float* KAP, const float* BETA, const float* WVEC,
    const float* CC, const float* UT,
    const float* lng, const float* lnb, int tokm, int t){
  const float ISQ = 0.17677669529663687f;
  for (int blk=0; blk<2; blk++){
    const float* src = blk ? rrow : xrow;
    int hh=t>>5, j=t&31;
    float part=0.f;
    for (int jj=j; jj<256; jj+=32) part += src[jj]*KAP[(blk*8+hh)*256+jj];
    part = g32sum(part);
    float alpha = (part + BETA[blk*8+hh]) * ISQ;
    float s1 = (j<tokm)     ? alpha*WVEC[j]    : -3.4e38f;
    float s2 = (j+32<tokm)  ? alpha*WVEC[j+32] : -3.4e38f;
    float mx = g32max(fmaxf(s1,s2));
    float e1 = expf(s1-mx), e2 = expf(s2-mx);
    float sn = e1*((j<tokm)?WVEC[j]:0.f) + e2*((j+32<tokm)?WVEC[j+32]:0.f);
    float sd = e1+e2;
    sn=g32sum(sn); sd=g32sum(sd);
    if (j==0) m8[hh]=sn/sd;
    __syncthreads();
    float x_ = blk ? rrow[t] : xrow[t];
    float z = CC[blk*256+t] + x_;
#pragma unroll
    for (int h2=0;h2<8;h2++) z += m8[h2]*UT[(blk*8+h2)*256+t];
    float ssum=wredsum(z), ssq=wredsum(z*z);
    int lane=t&63, wid=t>>6;
    if (lane==0){ redv[wid]=ssum; redv[4+wid]=ssq; }
    __syncthreads();
    float ts=redv[0]+redv[1]+redv[2]+redv[3];
    float tq=redv[4]+redv[5]+redv[6]+redv[7];
    float mu=ts*(1.f/256.f);
    float var=tq*(1.f/256.f)-mu*mu;
    float rstd=1.f/sqrtf(var+1e-5f);
    float rv=(z-mu)*rstd*lng[blk*256+t]+lnb[blk*256+t];
    __syncthreads();
    rrow[t]=rv;
    __syncthreads();
  }
}

// fenced barrier (prelude only): WG0 master over NWG=129 arrivals
__device__ __forceinline__ void gbar_f(int* arr, int* rel, int ep){
  __syncthreads();
  if (threadIdx.x==0){
    __builtin_amdgcn_fence(__ATOMIC_RELEASE, "agent");
    __hip_atomic_store(arr + blockIdx.x*16, ep, __ATOMIC_RELAXED, __HIP_MEMORY_SCOPE_AGENT);
  }
  if (blockIdx.x==0){
    if (threadIdx.x < NWG){
      while (__hip_atomic_load(arr + threadIdx.x*16, __ATOMIC_RELAXED, __HIP_MEMORY_SCOPE_AGENT) != ep)
        __builtin_amdgcn_s_sleep(1);
    }
    __syncthreads();
    if (threadIdx.x==0)
      __hip_atomic_store(rel, ep, __ATOMIC_RELAXED, __HIP_MEMORY_SCOPE_AGENT);
  }
  if (threadIdx.x==0){
    while (__hip_atomic_load(rel, __ATOMIC_RELAXED, __HIP_MEMORY_SCOPE_AGENT) != ep)
      __builtin_amdgcn_s_sleep(1);
    __builtin_amdgcn_fence(__ATOMIC_ACQUIRE, "agent");
  }
  __syncthreads();
}

// worker loop barrier: arrive + poll own release line (master is WG128)
__device__ __forceinline__ void gbar_w(int* arr, int* relv, int ep){
  __syncthreads();   // drains vmcnt: sc1 stores LLC-visible before arrive
  if (threadIdx.x==0){
    st_fi(arr + blockIdx.x*16, ep);
    while (ld_fi(relv + blockIdx.x*16) != ep) __builtin_amdgcn_s_sleep(1);
  }
  __syncthreads();
}

extern "C" __global__ __launch_bounds__(256, 2)
void gen18124_kernel(const float* __restrict__ noise,
                     const float* __restrict__ iw, const float* __restrict__ ib,
                     const float* __restrict__ Wq, const float* __restrict__ bq,
                     const float* __restrict__ Wk, const float* __restrict__ bk,
                     const float* __restrict__ Wv, const float* __restrict__ bv,
                     const float* __restrict__ Wo, const float* __restrict__ bo,
                     const float* __restrict__ lng, const float* __restrict__ lnb,
                     const float* __restrict__ emb, const float* __restrict__ sw,
                     const float* __restrict__ sb,
                     int* __restrict__ out, float* __restrict__ ws)
{
  const float ISQ = 0.17677669529663687f; // 1/sqrt(32)
  __shared__ float sm[5376];
  __shared__ ull redU[4];
  __shared__ int winS;                    // worker: winner token after winner-barrier
  __shared__ int wms;                     // master: reduced winner
  extern __shared__ float swl[];          // [256][128] soft_W slice, 128KB

  // ---- workspace layout (floats) ----
  float* WVEC = ws;            // 64
  float* SKC  = ws+64;         // [2][256]
  float* SVC  = ws+576;        // [2][256]
  float* KAP  = ws+1088;       // [2][8][256]
  float* UT   = ws+5184;       // [2][8][256]
  float* CC   = ws+9280;       // [2][256]
  float* BETA = ws+9792;       // [2][8]
  int* ARR = (int*)(ws+10080); // 129*16 ints (arrive lines; ends 12144)
  int* REL = (int*)(ws+12144); // prelude single release line (16)
  ull* KEY = (ull*)(ws+12160); // 128 entries, stride 8 ull; ends 14208
  float* Yg  = ws+14208;       // [64][256]
  float* R1  = ws+30592;       // [64][256]
  float* QB  = ws+46976;       // [64][256]
  float* KB  = ws+63360;       // [64][256]
  float* VB  = ws+79744;       // [64][256]
  float* R2  = ws+96128;       // [64][256]
  float* Z2P = ws+112512;      // [8][64][256]
  float* Z3P = ws+243584;      // [8][256]   ends 245632
  int* RELV  = (int*)(ws+245632); // 128*16 per-WG loop release lines
  int* RELV2 = (int*)(ws+247680); // 128*16 per-WG winner release lines (payload)
  int* Z3F2  = (int*)(ws+249728); // [8][128]*16 fan-out mini flags; ends 266112

  const int g = blockIdx.x, t = threadIdx.x;
  int ep = 0;

  // ---- soft_W slice -> LDS (workers only) ----
  if (g < NWRK){
    const int base = g*125;
#pragma unroll 8
    for (int i=t; i<256*128; i+=NT){
      int e=i>>7, c=i&127;
      float val = 0.f;
      if (c<125) val = sw[e*16000 + base + c];
      swl[i]=val;
    }
  }

  // ================= Prelude A: colsums, wvec, Y0, init (workers) ==========
  if (g < NWRK){
    int c0 = 2*g;
    float a0=Wk[t*256+c0],       a1=Wk[t*256+c0+1];
    float a2=Wk[65536+t*256+c0], a3=Wk[65536+t*256+c0+1];
    float a4=Wv[t*256+c0],       a5=Wv[t*256+c0+1];
    float a6=Wv[65536+t*256+c0], a7=Wv[65536+t*256+c0+1];
    a0=wredsum(a0); a1=wredsum(a1); a2=wredsum(a2); a3=wredsum(a3);
    a4=wredsum(a4); a5=wredsum(a5); a6=wredsum(a6); a7=wredsum(a7);
    int lane=t&63, wid=t>>6;
    if (lane==0){
      sm[wid*8+0]=a0; sm[wid*8+1]=a1; sm[wid*8+2]=a2; sm[wid*8+3]=a3;
      sm[wid*8+4]=a4; sm[wid*8+5]=a5; sm[wid*8+6]=a6; sm[wid*8+7]=a7;
    }
    __syncthreads();
    if (t<8){
      float s=sm[t]+sm[8+t]+sm[16+t]+sm[24+t];
      if (t<4) SKC[(t>>1)*256 + c0 + (t&1)] = s;
      else     SVC[((t-4)>>1)*256 + c0 + ((t-4)&1)] = s;
    }
    __syncthreads();
    if (g==0){
      // zero the monotone fan-out flags (Z3F2 uses < tok compares)
      for (int i=t;i<16384;i+=NT) Z3F2[i]=0;
      float* wl = sm+64;
      if (t<64) wl[t] = noise[t];
      __syncthreads();
      for (int i=0;i<4;i++){
        float acc=0.f;
        if (t<64){
          for (int in_=0;in_<64;in_++) acc += wl[in_]*iw[(i*64+in_)*64+t];
          acc += ib[i*64+t];
        }
        __syncthreads();
        if (t<64) wl[t]=acc;
        __syncthreads();
      }
      if (t<64) WVEC[t]=wl[t];
    }
    if (g==1){
      Yg[t] = emb[t] + pe_val(0,t);
      if (t==0) out[0]=0;
    }
  }
  gbar_f(ARR,REL,++ep);

  // ================= Prelude B: KAP / UT / CC / BETA tables (workers) ======
  if (g < NWRK){
    int c0 = 2*g;
    float p00 = bv[t]    *Wo[t*256+c0],        p01 = bv[t]    *Wo[t*256+c0+1];
    float p10 = bv[256+t]*Wo[65536+t*256+c0],  p11 = bv[256+t]*Wo[65536+t*256+c0+1];
    p00=wredsum(p00); p01=wredsum(p01); p10=wredsum(p10); p11=wredsum(p11);
    int lane=t&63, wid=t>>6;
    if (lane==0){ sm[wid*4+0]=p00; sm[wid*4+1]=p01; sm[wid*4+2]=p10; sm[wid*4+3]=p11; }
    __syncthreads();
    if (t<4){
      float s=sm[t]+sm[4+t]+sm[8+t]+sm[12+t];
      int i=t>>1, cl=t&1;
      CC[i*256+c0+cl] = s + bo[i*256+c0+cl];
    }
    if (t<32){
      int i=t>>4, h2=(t>>1)&7, c=c0+(t&1);
      float s=0.f;
      for (int e2=0;e2<32;e2++) s += SVC[i*256+h2*32+e2]*Wo[i*65536+(h2*32+e2)*256+c];
      UT[(i*8+h2)*256+c]=s;
    }
    if (t>=32 && t<64){
      int u=t-32, i=u>>4, h2=(u>>1)&7, e=c0+(u&1);
      float s=0.f;
      for (int c2=0;c2<32;c2++) s += Wq[i*65536+e*256+h2*32+c2]*SKC[i*256+h2*32+c2];
      KAP[(i*8+h2)*256+e]=s;
    }
    if (g==0 && t>=64 && t<80){
      int u=t-64, i=u>>3, h2=u&7;
      float s=0.f;
      for (int c2=0;c2<32;c2++) s += bq[i*256+h2*32+c2]*SKC[i*256+h2*32+c2];
      BETA[i*8+h2]=s;
    }
  }
  gbar_f(ARR,REL,++ep);

  // ================= Pre-loop: A for row 0, mask 1 (WG 0) =================
  if (g==0){
    float* axr=sm; float* arr=sm+256; float* am8=sm+512; float* ard=sm+528;
    axr[t]=ld_c(&Yg[t]);
    __syncthreads();
    a_chain(axr,arr,am8,ard, KAP,BETA,WVEC,CC,UT,lng,lnb, 1, t);
    st_c(&R1[t], arr[t]);
  }
  gbar_f(ARR,REL,++ep);

  // =========================== MASTER (WG 128) =============================
  if (g == NWRK){
    for (int tok=1; tok<64; tok++){
      // 3 regular barriers
      for (int b=0;b<3;b++){
        ++ep;
        if (t < NWRK){ while (ld_fi(ARR + t*16) != ep) {} }   // tight pre-spin
        __syncthreads();
        if (t < NWRK) st_fi(RELV + t*16, ep);
        __syncthreads();
      }
      // winner barrier: scan, reduce KEY, fan out payload
      ++ep;
      if (t < NWRK){ while (ld_fi(ARR + t*16) != ep) {} }
      __syncthreads();
      ull k = 0ull;
      if (t < NWRK) k = ld_u64(KEY + t*8);
#pragma unroll
      for (int m=32;m;m>>=1){
        ull o=shflx64(k,m);
        k = (o>k)? o : k;
      }
      if ((t&63)==0 && t<NWRK) redU[t>>6]=k;
      __syncthreads();
      if (t==0){
        ull kk=redU[0];
        if (redU[1]>kk) kk=redU[1];
        wms = (int)(~(unsigned int)(kk & 0xffffffffull));
      }
      __syncthreads();
      if (t < NWRK) st_fi(RELV2 + t*16, (ep<<14) | wms);
      __syncthreads();
    }
    return;
  }

  // =========================== WORKERS (WGs 0..127) ========================
  const int h  = g&7;
  const int rg = g>>3;

  for (int tok=1; tok<64; tok++){
    const int n = tok-1;

    // ---- Stage B: [redundant A for row n, token from winS] + self0 QKV proj ----
    {
      float* rows4 = sm; // [4][256]
#pragma unroll
      for (int jj=0;jj<4;jj++) rows4[jj*256+t] = ld_c(&R1[(rg+16*jj)*256+t]);
      if (tok>1 && rg==(n&15)){
        float* axr=sm+2700; float* arr2=sm+2956; float* am8=sm+3212; float* ard=sm+3224;
        int v = winS;                    // broadcast by previous winner-barrier
        if (h==0 && t==0) out[n]=v;
        axr[t] = emb[v*256+t] + pe_val(n,t);
        if (h==0) st_c(&Yg[n*256+t], axr[t]);
        __syncthreads();
        a_chain(axr,arr2,am8,ard, KAP,BETA,WVEC,CC,UT,lng,lnb, tok, t);
        rows4[(n>>4)*256+t] = arr2[t];
        if (h==0) st_c(&R1[n*256+t], arr2[t]);
      }
      __syncthreads();
      int c=t&31, epp=t>>5;
      const int col=h*32+c;
      float aq[4]={0,0,0,0}, ak[4]={0,0,0,0}, av[4]={0,0,0,0};
#pragma unroll 8
      for (int e=epp*32; e<epp*32+32; e++){
        float wq_=Wq[e*256+col], wk_=Wk[e*256+col], wv_=Wv[e*256+col];
#pragma unroll
        for (int jj=0;jj<4;jj++){ float r=rows4[jj*256+e]; aq[jj]+=r*wq_; ak[jj]+=r*wk_; av[jj]+=r*wv_; }
      }
#pragma unroll
      for (int jj=0;jj<4;jj++){
        aq[jj]+=__shfl_xor(aq[jj],32,64);
        ak[jj]+=__shfl_xor(ak[jj],32,64);
        av[jj]+=__shfl_xor(av[jj],32,64);
      }
      float4* redq=(float4*)(sm+1056); float4* redk=(float4*)(sm+1568); float4* redv4=(float4*)(sm+2080);
      int lane=t&63, wid=t>>6;
      if (lane<32){
        redq[wid*32+lane]=make_float4(aq[0],aq[1],aq[2],aq[3]);
        redk[wid*32+lane]=make_float4(ak[0],ak[1],ak[2],ak[3]);
        redv4[wid*32+lane]=make_float4(av[0],av[1],av[2],av[3]);
      }
      __syncthreads();
      if (t<32){
        float4 A=redq[t],B4=redq[32+t],C4=redq[64+t],D4=redq[96+t];
        float sq[4]={A.x+B4.x+C4.x+D4.x, A.y+B4.y+C4.y+D4.y, A.z+B4.z+C4.z+D4.z, A.w+B4.w+C4.w+D4.w};
        A=redk[t];B4=redk[32+t];C4=redk[64+t];D4=redk[96+t];
        float sk[4]={A.x+B4.x+C4.x+D4.x, A.y+B4.y+C4.y+D4.y, A.z+B4.z+C4.z+D4.z, A.w+B4.w+C4.w+D4.w};
        A=redv4[t];B4=redv4[32+t];C4=redv4[64+t];D4=redv4[96+t];
        float sv[4]={A.x+B4.x+C4.x+D4.x, A.y+B4.y+C4.y+D4.y, A.z+B4.z+C4.z+D4.z, A.w+B4.w+C4.w+D4.w};
        int cc=h*32+t;
        float bq_=bq[cc], bk_=bk[cc], bv_=bv[cc];
#pragma unroll
        for (int jj=0;jj<4;jj++){
          int q_=rg+16*jj;
          if (q_<tok){
            st_c(&QB[q_*256+cc], sq[jj]+bq_);
            st_c(&KB[q_*256+cc], sk[jj]+bk_);
            st_c(&VB[q_*256+cc], sv[jj]+bv_);
          }
        }
      }
    }
    gbar_w(ARR,RELV,++ep);

    // ---- Stage C: self0 attention + per-head partial O-proj -> Z2P ----
    {
      float* Ks=sm; float* Vs=sm+2112; float* qrow=sm+4224; float* arow=sm+4352; float* o2s=sm+4608;
      int k=t>>2, f0=(t&3)*8;
      if (k<tok){
#pragma unroll
        for (int i2=0;i2<8;i2++){
          Ks[k*33+f0+i2]=ld_c(&KB[k*256+h*32+f0+i2]);
          Vs[k*33+f0+i2]=ld_c(&VB[k*256+h*32+f0+i2]);
        }
      }
      if (t<128){ int jj=t>>5, c=t&31; int q_=rg+16*jj; if (q_<tok) qrow[jj*32+c]=ld_c(&QB[q_*256+h*32+c]); }
      __syncthreads();
      int w=t>>6, lane=t&63; int q_=rg+16*w; bool ok=q_<tok;
      float sc=-3.4e38f;
      if (ok && lane<tok){
        sc=0.f;
#pragma unroll
        for (int c2=0;c2<32;c2++) sc+=qrow[w*32+c2]*Ks[lane*33+c2];
        sc*=ISQ;
      }
      float mx=wredmax(sc);
      float ex=(ok&&lane<tok)? expf(sc-mx):0.f;
      float sd=wredsum(ex);
      arow[w*64+lane]= ok ? ex/sd : 0.f;
      __syncthreads();
      int j=lane&31, half=lane>>5;
      float oa=0.f;
      if (ok){ for (int k2=half;k2<tok;k2+=2) oa+=arow[w*64+k2]*Vs[k2*33+j]; }
      oa += __shfl_xor(oa,32,64);
      if (lane<32) o2s[w*32+j]=oa;
      __syncthreads();
      float acc[4]={0,0,0,0};
#pragma unroll 8
      for (int j2=0;j2<32;j2++){
        float wv_=Wo[(h*32+j2)*256+t];
#pragma unroll
        for (int jj=0;jj<4;jj++) acc[jj]+=o2s[jj*32+j2]*wv_;
      }
#pragma unroll
      for (int jj=0;jj<4;jj++){ int q2=rg+16*jj; if (q2<tok) st_c(&Z2P[(h*64+q2)*256+t], acc[jj]); }
    }
    gbar_w(ARR,RELV,++ep);

    // ---- Stage E: z2 assemble + LN -> r2 ; self1 K/V proj (+Q for row n) ----
    {
      float* rows4=sm; float* mus=sm+1024;
#pragma unroll
      for (int jj=0;jj<4;jj++){
        int q_=rg+16*jj;
        float z = bo[t] + ld_c(&R1[q_*256+t]);
#pragma unroll
        for (int h2=0;h2<8;h2++) z += ld_c(&Z2P[(h2*64+q_)*256+t]);
        rows4[jj*256+t]=z;
      }
      __syncthreads();
      {
        int w=t>>6, lane=t&63;
        float v0=rows4[w*256+lane], v1=rows4[w*256+64+lane], v2=rows4[w*256+128+lane], v3=rows4[w*256+192+lane];
        float s=v0+v1+v2+v3, sq2=v0*v0+v1*v1+v2*v2+v3*v3;
        s=wredsum(s); sq2=wredsum(sq2);
        if (lane==0){
          float mu=s*(1.f/256.f);
          float var=sq2*(1.f/256.f)-mu*mu;
          mus[w*2]=mu; mus[w*2+1]=1.f/sqrtf(var+1e-5f);
        }
      }
      __syncthreads();
#pragma unroll
      for (int jj=0;jj<4;jj++){
        float mu=mus[jj*2], rstd=mus[jj*2+1];
        float val=(rows4[jj*256+t]-mu)*rstd*lng[t]+lnb[t];
        rows4[jj*256+t]=val;
        int q_=rg+16*jj;
        if (h==0 && q_==n) st_c(&R2[q_*256+t], val);
      }
      __syncthreads();
      int c=t&31, epp=t>>5;
      const int col=h*32+c;
      float aq[4]={0,0,0,0}, ak[4]={0,0,0,0}, av[4]={0,0,0,0};
#pragma unroll 8
      for (int e=epp*32; e<epp*32+32; e++){
        float wq_=Wq[65536+e*256+col], wk_=Wk[65536+e*256+col], wv_=Wv[65536+e*256+col];
#pragma unroll
        for (int jj=0;jj<4;jj++){ float r=rows4[jj*256+e]; aq[jj]+=r*wq_; ak[jj]+=r*wk_; av[jj]+=r*wv_; }
      }
#pragma unroll
      for (int jj=0;jj<4;jj++){
        aq[jj]+=__shfl_xor(aq[jj],32,64);
        ak[jj]+=__shfl_xor(ak[jj],32,64);
        av[jj]+=__shfl_xor(av[jj],32,64);
      }
      float4* redq=(float4*)(sm+1056); float4* redk=(float4*)(sm+1568); float4* redv4=(float4*)(sm+2080);
      int lane=t&63, wid=t>>6;
      if (lane<32){
        redq[wid*32+lane]=make_float4(aq[0],aq[1],aq[2],aq[3]);
        redk[wid*32+lane]=make_float4(ak[0],ak[1],ak[2],ak[3]);
        redv4[wid*32+lane]=make_float4(av[0],av[1],av[2],av[3]);
      }
      __syncthreads();
      if (t<32){
        float4 A=redq[t],B4=redq[32+t],C4=redq[64+t],D4=redq[96+t];
        float sq[4]={A.x+B4.x+C4.x+D4.x, A.y+B4.y+C4.y+D4.y, A.z+B4.z+C4.z+D4.z, A.w+B4.w+C4.w+D4.w};
        A=redk[t];B4=redk[32+t];C4=redk[64+t];D4=redk[96+t];
        float sk[4]={A.x+B4.x+C4.x+D4.x, A.y+B4.y+C4.y+D4.y, A.z+B4.z+C4.z+D4.z, A.w+B4.w+C4.w+D4.w};
        A=redv4[t];B4=redv4[32+t];C4=redv4[64+t];D4=redv4[96+t];
        float sv[4]={A.x+B4.x+C4.x+D4.x, A.y+B4.y+C4.y+D4.y, A.z+B4.z+C4.z+D4.z, A.w+B4.w+C4.w+D4.w};
        int cc=h*32+t;
#pragma unroll
        for (int jj=0;jj<4;jj++){
          int q_=rg+16*jj;
          if (q_<tok){
            st_c(&KB[q_*256+cc], sk[jj]+bk[256+cc]);
            st_c(&VB[q_*256+cc], sv[jj]+bv[256+cc]);
            if (q_==n) st_c(&QB[q_*256+cc], sq[jj]+bq[256+cc]);
          }
        }
      }
    }
    gbar_w(ARR,RELV,++ep);

    // ---- Stage H': F (WGs 0..7) || A-next (WGs 64..126) ; all: mini, logits ----
    {
      float resid = ld_c(&R2[n*256+t]);   // early issue; valid after E-barrier
      if (g < 8){
        const int hh = g;
        float* Ks=sm; float* Vs=sm+2112; float* qn=sm+4224; float* arow=sm+4352; float* o3s=sm+4608;
        int k=t>>2, f0=(t&3)*8;
        if (k<tok){
#pragma unroll
          for (int i2=0;i2<8;i2++){
            Ks[k*33+f0+i2]=ld_c(&KB[k*256+hh*32+f0+i2]);
            Vs[k*33+f0+i2]=ld_c(&VB[k*256+hh*32+f0+i2]);
          }
        }
        if (t<32) qn[t]=ld_c(&QB[n*256+hh*32+t]);
        __syncthreads();
        int lane=t&63, w=t>>6;
        if (w==0){
          float sc=-3.4e38f;
          if (lane<tok){
            sc=0.f;
#pragma unroll
            for (int c2=0;c2<32;c2++) sc+=qn[c2]*Ks[lane*33+c2];
            sc*=ISQ;
          }
          float mx=wredmax(sc);
          float ex=(lane<tok)? expf(sc-mx):0.f;
          float sd=wredsum(ex);
          arow[lane]=ex/sd;
        }
        __syncthreads();
        if (w==0){
          int j=lane&31, half=lane>>5;
          float oa=0.f;
          for (int k2=half;k2<tok;k2+=2) oa+=arow[k2]*Vs[k2*33+j];
          oa+=__shfl_xor(oa,32,64);
          if (lane<32) o3s[j]=oa;
        }
        __syncthreads();
        float acc=0.f;
#pragma unroll 8
        for (int j2=0;j2<32;j2++) acc+=o3s[j2]*Wo[65536+(hh*32+j2)*256+t];
        st_c(&Z3P[hh*256+t], acc);
        __syncthreads();            // drain Z3P stores to LLC
        // fan-out: one flag line per consumer WG (uncontended polling)
        if (t < NWRK) st_fi(Z3F2 + (hh*NWRK + t)*16, tok);
      } else if (g>=64 && g<127){
        const int q = g-64;
        if (q < tok && tok < 63){
          float* axr=sm; float* arr2=sm+256; float* am8=sm+512; float* ard=sm+528;
          axr[t]=ld_c(&Yg[q*256+t]);
          __syncthreads();
          a_chain(axr,arr2,am8,ard, KAP,BETA,WVEC,CC,UT,lng,lnb, tok+1, t);
          st_c(&R1[q*256+t], arr2[t]);
        }
      }
      // mini-barrier: poll OWN 8 per-consumer flag lines (monotone = tok)
      if (t<8){ while (ld_fi(Z3F2 + (t*NWRK + g)*16) < tok) __builtin_amdgcn_s_sleep(1); }
      __syncthreads();
      float* outn=sm; float* redv=sm+256; float* pp=sm+512;
      float z = bo[256+t] + resid;
#pragma unroll
      for (int h2=0;h2<8;h2++) z += ld_c(&Z3P[h2*256+t]);
      float s=wredsum(z), sq2=wredsum(z*z);
      int lane=t&63, wid=t>>6;
      if (lane==0){ redv[wid]=s; redv[4+wid]=sq2; }
      __syncthreads();
      float ts=redv[0]+redv[1]+redv[2]+redv[3];
      float tq=redv[4]+redv[5]+redv[6]+redv[7];
      float mu=ts*(1.f/256.f);
      float var=tq*(1.f/256.f)-mu*mu;
      float rstd=1.f/sqrtf(var+1e-5f);
      outn[t]=(z-mu)*rstd*lng[256+t]+lnb[256+t];
      __syncthreads();
      const int c = t & 127, half = t >> 7;
      float acc = 0.f;
      if (c < 125){
        const int e0 = half*128;
#pragma unroll 8
        for (int e=e0; e<e0+128; e++) acc += outn[e]*swl[e*128+c];
      }
      if (half==1 && c<125) pp[c]=acc;
      __syncthreads();
      ull key=0ull;
      if (half==0 && c<125){
        int v=g*125+c;
        float a2 = acc + pp[c] + sb[v];
        unsigned int fb=__float_as_uint(a2);
        fb = (fb&0x80000000u)? ~fb : (fb|0x80000000u);
        key=(((ull)fb)<<32) | (ull)(~(unsigned int)v);
      }
#pragma unroll
      for (int m=32;m;m>>=1){
        ull o=shflx64(key,m);
        key = (o>key)? o : key;
      }
      if (lane==0) redU[wid]=key;
      __syncthreads();
      if (t==0){
        ull kk=redU[0];
        if (redU[1]>kk) kk=redU[1];
        if (redU[2]>kk) kk=redU[2];
        if (redU[3]>kk) kk=redU[3];
        st_u64(KEY + g*8, kk);       // private line; no contention
      }
    }
    // ---- winner-barrier (worker side): arrive; poll own payload line ----
    {
      ++ep;
      __syncthreads();   // drains KEY store + all sc1 stage stores
      if (t==0){
        st_fi(ARR + g*16, ep);
        int r;
        while (((r = ld_fi(RELV2 + g*16)) >> 14) != ep) __builtin_amdgcn_s_sleep(1);
        winS = r & 0x3fff;
      }
      __syncthreads();
    }
  }

  // epilogue: final winner (broadcast by the last winner-barrier)
  if (g==0 && t==0) out[63] = winS;
}

extern "C" void kernel_launch(void* const* d_in, const int* in_sizes, int n_in,
                              void* d_out, int out_size, void* d_ws, size_t ws_size,
                              hipStream_t stream)
{
  (void)in_sizes; (void)n_in; (void)out_size; (void)ws_size;
  hipLaunchKernelGGL(gen18124_kernel, dim3(NWG), dim3(NT), 131072, stream,
    (const float*)d_in[0],  (const float*)d_in[1],  (const float*)d_in[2],
    (const float*)d_in[3],  (const float*)d_in[4],  (const float*)d_in[5],
    (const float*)d_in[6],  (const float*)d_in[7],  (const float*)d_in[8],
    (const float*)d_in[9],  (const float*)d_in[10], (const float*)d_in[11],
    (const float*)d_in[12], (const float*)d_in[13], (const float*)d_in[14],
    (const float*)d_in[15], (int*)d_out, (float*)d_ws);
}

// Round 13
// 3561.469 us; speedup vs baseline: 1.1372x; 1.1372x over previous
//
#include <hip/hip_runtime.h>
#include <stdint.h>

// R16 = R15 (best: 3917us steady) + two bit-safe micro-levers:
//  (1) C/F K/V staging: 16 scalar agent-scope loads -> 8 paired ull loads
//      (consecutive addresses, 32B aligned; bit-exact).
//  (2) Folded-LN logits: swl holds lng2-folded soft_W; prelude computes
//      S1[c]=sum_e w'[e][c], CONST[c]=sum_e lnb2[e]*sw[e][c]+sb[c] per WG.
//      logit_c = rstd*(z.w' - mu*S1[c]) + CONST[c] -> GEMV runs on RAW z,
//      deleting one __syncthreads + per-element LN + the sb load from the
//      H' serial tail.
//  Everything else identical to R15 (129 WGs, dedicated pre-spinning master,
//  per-consumer release lines, fan-out mini, A-hiding under H').

#define NWG 129
#define NWRK 128
#define NT 256

typedef unsigned long long ull;

__device__ __forceinline__ float ld_c(const float* p){
  return __hip_atomic_load(p, __ATOMIC_RELAXED, __HIP_MEMORY_SCOPE_AGENT);
}
__device__ __forceinline__ void st_c(float* p, float v){
  __hip_atomic_store(p, v, __ATOMIC_RELAXED, __HIP_MEMORY_SCOPE_AGENT);
}
__device__ __forceinline__ int ld_fi(const int* p){
  return __hip_atomic_load(p, __ATOMIC_RELAXED, __HIP_MEMORY_SCOPE_AGENT);
}
__device__ __forceinline__ void st_fi(int* p, int v){
  __hip_atomic_store(p, v, __ATOMIC_RELAXED, __HIP_MEMORY_SCOPE_AGENT);
}
__device__ __forceinline__ ull ld_u64(const ull* p){
  return __hip_atomic_load(p, __ATOMIC_RELAXED, __HIP_MEMORY_SCOPE_AGENT);
}
__device__ __forceinline__ void st_u64(ull* p, ull v){
  __hip_atomic_store(p, v, __ATOMIC_RELAXED, __HIP_MEMORY_SCOPE_AGENT);
}

__device__ __forceinline__ float wredsum(float v){
#pragma unroll
  for (int m=32;m;m>>=1) v += __shfl_xor(v,m,64);
  return v;
}
__device__ __forceinline__ float wredmax(float v){
#pragma unroll
  for (int m=32;m;m>>=1) v = fmaxf(v,__shfl_xor(v,m,64));
  return v;
}
__device__ __forceinline__ float g32sum(float v){
#pragma unroll
  for (int m=16;m;m>>=1) v += __shfl_xor(v,m,64);
  return v;
}
__device__ __forceinline__ float g32max(float v){
#pragma unroll
  for (int m=16;m;m>>=1) v = fmaxf(v,__shfl_xor(v,m,64));
  return v;
}
__device__ __forceinline__ ull shflx64(ull v,int m){
  unsigned int lo=(unsigned int)(v&0xffffffffull), hi=(unsigned int)(v>>32);
  lo=__shfl_xor(lo,m,64); hi=__shfl_xor(hi,m,64);
  return (((ull)hi)<<32)|(ull)lo;
}

__device__ __forceinline__ float pe_val(int l, int e){
  int j = e >> 1;
  float dv = expf((float)(2*j) * (-0.035977892078031970f));
  float arg = (float)l * dv;
  return (e & 1) ? cosf(arg) : sinf(arg);
}

// A-chain: cross blocks x2 (rank-1 collapsed) + LN -> rrow. WG-uniform.
__device__ __forceinline__ void a_chain(const float* xrow, float* rrow,
    float* m8, float* redv,
    const float* KAP, const float* BETA, const float* WVEC,
    const float* CC, const float* UT,
    const float* lng, const float* lnb, int tokm, int t){
  const float ISQ = 0.17677669529663687f;
  for (int blk=0; blk<2; blk++){
    const float* src = blk ? rrow : xrow;
    int hh=t>>5, j=t&31;
    float part=0.f;
    for (int jj=j; jj<256; jj+=32) part += src[jj]*KAP[(blk*8+hh)*256+jj];
    part = g32sum(part);
    float alpha = (part + BETA[blk*8+hh]) * ISQ;
    float s1 = (j<tokm)     ? alpha*WVEC[j]    : -3.4e38f;
    float s2 = (j+32<tokm)  ? alpha*WVEC[j+32] : -3.4e38f;
    float mx = g32max(fmaxf(s1,s2));
    float e1 = expf(s1-mx), e2 = expf(s2-mx);
    float sn = e1*((j<tokm)?WVEC[j]:0.f) + e2*((j+32<tokm)?WVEC[j+32]:0.f);
    float sd = e1+e2;
    sn=g32sum(sn); sd=g32sum(sd);
    if (j==0) m8[hh]=sn/sd;
    __syncthreads();
    float x_ = blk ? rrow[t] : xrow[t];
    float z = CC[blk*256+t] + x_;
#pragma unroll
    for (int h2=0;h2<8;h2++) z += m8[h2]*UT[(blk*8+h2)*256+t];
    float ssum=wredsum(z), ssq=wredsum(z*z);
    int lane=t&63, wid=t>>6;
    if (lane==0){ redv[wid]=ssum; redv[4+wid]=ssq; }
    __syncthreads();
    float ts=redv[0]+redv[1]+redv[2]+redv[3];
    float tq=redv[4]+redv[5]+redv[6]+redv[7];
    float mu=ts*(1.f/256.f);
    float var=tq*(1.f/256.f)-mu*mu;
    float rstd=1.f/sqrtf(var+1e-5f);
    float rv=(z-mu)*rstd*lng[blk*256+t]+lnb[blk*256+t];
    __syncthreads();
    rrow[t]=rv;
    __syncthreads();
  }
}

// fenced barrier (prelude only): WG0 master over NWG=129 arrivals
__device__ __forceinline__ void gbar_f(int* arr, int* rel, int ep){
  __syncthreads();
  if (threadIdx.x==0){
    __builtin_amdgcn_fence(__ATOMIC_RELEASE, "agent");
    __hip_atomic_store(arr + blockIdx.x*16, ep, __ATOMIC_RELAXED, __HIP_MEMORY_SCOPE_AGENT);
  }
  if (blockIdx.x==0){
    if (threadIdx.x < NWG){
      while (__hip_atomic_load(arr + threadIdx.x*16, __ATOMIC_RELAXED, __HIP_MEMORY_SCOPE_AGENT) != ep)
        __builtin_amdgcn_s_sleep(1);
    }
    __syncthreads();
    if (threadIdx.x==0)
      __hip_atomic_store(rel, ep, __ATOMIC_RELAXED, __HIP_MEMORY_SCOPE_AGENT);
  }
  if (threadIdx.x==0){
    while (__hip_atomic_load(rel, __ATOMIC_RELAXED, __HIP_MEMORY_SCOPE_AGENT) != ep)
      __builtin_amdgcn_s_sleep(1);
    __builtin_amdgcn_fence(__ATOMIC_ACQUIRE, "agent");
  }
  __syncthreads();
}

// worker loop barrier: arrive + poll own release line (master is WG128)
__device__ __forceinline__ void gbar_w(int* arr, int* relv, int ep){
  __syncthreads();   // drains vmcnt: sc1 stores LLC-visible before arrive
  if (threadIdx.x==0){
    st_fi(arr + blockIdx.x*16, ep);
    while (ld_fi(relv + blockIdx.x*16) != ep) __builtin_amdgcn_s_sleep(1);
  }
  __syncthreads();
}

extern "C" __global__ __launch_bounds__(256, 2)
void gen18124_kernel(const float* __restrict__ noise,
                     const float* __restrict__ iw, const float* __restrict__ ib,
                     const float* __restrict__ Wq, const float* __restrict__ bq,
                     const float* __restrict__ Wk, const float* __restrict__ bk,
                     const float* __restrict__ Wv, const float* __restrict__ bv,
                     const float* __restrict__ Wo, const float* __restrict__ bo,
                     const float* __restrict__ lng, const float* __restrict__ lnb,
                     const float* __restrict__ emb, const float* __restrict__ sw,
                     const float* __restrict__ sb,
                     int* __restrict__ out, float* __restrict__ ws)
{
  const float ISQ = 0.17677669529663687f; // 1/sqrt(32)
  __shared__ float sm[5376];
  __shared__ float S1s[128];     // per-col sum of folded weights (own 125 cols)
  __shared__ float CONSTs[128];  // per-col lnb-fold + sb
  __shared__ ull redU[4];
  __shared__ int winS;
  __shared__ int wms;
  extern __shared__ float swl[]; // [256][128] lng2-FOLDED soft_W slice, 128KB

  // ---- workspace layout (floats) ----
  float* WVEC = ws;            // 64
  float* SKC  = ws+64;         // [2][256]
  float* SVC  = ws+576;        // [2][256]
  float* KAP  = ws+1088;       // [2][8][256]
  float* UT   = ws+5184;       // [2][8][256]
  float* CC   = ws+9280;       // [2][256]
  float* BETA = ws+9792;       // [2][8]
  int* ARR = (int*)(ws+10080); // 129*16 ints (arrive lines; ends 12144)
  int* REL = (int*)(ws+12144); // prelude single release line (16)
  ull* KEY = (ull*)(ws+12160); // 128 entries, stride 8 ull; ends 14208
  float* Yg  = ws+14208;       // [64][256]
  float* R1  = ws+30592;       // [64][256]
  float* QB  = ws+46976;       // [64][256]
  float* KB  = ws+63360;       // [64][256]
  float* VB  = ws+79744;       // [64][256]
  float* R2  = ws+96128;       // [64][256]
  float* Z2P = ws+112512;      // [8][64][256]
  float* Z3P = ws+243584;      // [8][256]   ends 245632
  int* RELV  = (int*)(ws+245632); // 128*16 per-WG loop release lines
  int* RELV2 = (int*)(ws+247680); // 128*16 per-WG winner release lines (payload)
  int* Z3F2  = (int*)(ws+249728); // [8][128]*16 fan-out mini flags; ends 266112

  const int g = blockIdx.x, t = threadIdx.x;
  int ep = 0;

  // ---- soft_W slice -> LDS, folded with lng2 (workers only) ----
  if (g < NWRK){
    const int base = g*125;
#pragma unroll 8
    for (int i=t; i<256*128; i+=NT){
      int e=i>>7, c=i&127;
      float val = 0.f;
      if (c<125) val = lng[256+e]*sw[e*16000 + base + c];
      swl[i]=val;
    }
    __syncthreads();
    // per-col S1 (sum of folded weights) + CONST (lnb fold + sb)
    if (t < 128){
      float s1v=0.f, cov=0.f;
      if (t < 125){
        const int col = base + t;
        for (int e=0;e<256;e++){
          s1v += swl[e*128+t];
          cov += lnb[256+e]*sw[e*16000+col];
        }
        cov += sb[col];
      }
      S1s[t]=s1v; CONSTs[t]=cov;
    }
  }

  // ================= Prelude A: colsums, wvec, Y0, init (workers) ==========
  if (g < NWRK){
    __syncthreads();
    int c0 = 2*g;
    float a0=Wk[t*256+c0],       a1=Wk[t*256+c0+1];
    float a2=Wk[65536+t*256+c0], a3=Wk[65536+t*256+c0+1];
    float a4=Wv[t*256+c0],       a5=Wv[t*256+c0+1];
    float a6=Wv[65536+t*256+c0], a7=Wv[65536+t*256+c0+1];
    a0=wredsum(a0); a1=wredsum(a1); a2=wredsum(a2); a3=wredsum(a3);
    a4=wredsum(a4); a5=wredsum(a5); a6=wredsum(a6); a7=wredsum(a7);
    int lane=t&63, wid=t>>6;
    if (lane==0){
      sm[wid*8+0]=a0; sm[wid*8+1]=a1; sm[wid*8+2]=a2; sm[wid*8+3]=a3;
      sm[wid*8+4]=a4; sm[wid*8+5]=a5; sm[wid*8+6]=a6; sm[wid*8+7]=a7;
    }
    __syncthreads();
    if (t<8){
      float s=sm[t]+sm[8+t]+sm[16+t]+sm[24+t];
      if (t<4) SKC[(t>>1)*256 + c0 + (t&1)] = s;
      else     SVC[((t-4)>>1)*256 + c0 + ((t-4)&1)] = s;
    }
    __syncthreads();
    if (g==0){
      // zero the monotone fan-out flags (Z3F2 uses < tok compares)
      for (int i=t;i<16384;i+=NT) Z3F2[i]=0;
      float* wl = sm+64;
      if (t<64) wl[t] = noise[t];
      __syncthreads();
      for (int i=0;i<4;i++){
        float acc=0.f;
        if (t<64){
          for (int in_=0;in_<64;in_++) acc += wl[in_]*iw[(i*64+in_)*64+t];
          acc += ib[i*64+t];
        }
        __syncthreads();
        if (t<64) wl[t]=acc;
        __syncthreads();
      }
      if (t<64) WVEC[t]=wl[t];
    }
    if (g==1){
      Yg[t] = emb[t] + pe_val(0,t);
      if (t==0) out[0]=0;
    }
  }
  gbar_f(ARR,REL,++ep);

  // ================= Prelude B: KAP / UT / CC / BETA tables (workers) ======
  if (g < NWRK){
    int c0 = 2*g;
    float p00 = bv[t]    *Wo[t*256+c0],        p01 = bv[t]    *Wo[t*256+c0+1];
    float p10 = bv[256+t]*Wo[65536+t*256+c0],  p11 = bv[256+t]*Wo[65536+t*256+c0+1];
    p00=wredsum(p00); p01=wredsum(p01); p10=wredsum(p10); p11=wredsum(p11);
    int lane=t&63, wid=t>>6;
    if (lane==0){ sm[wid*4+0]=p00; sm[wid*4+1]=p01; sm[wid*4+2]=p10; sm[wid*4+3]=p11; }
    __syncthreads();
    if (t<4){
      float s=sm[t]+sm[4+t]+sm[8+t]+sm[12+t];
      int i=t>>1, cl=t&1;
      CC[i*256+c0+cl] = s + bo[i*256+c0+cl];
    }
    if (t<32){
      int i=t>>4, h2=(t>>1)&7, c=c0+(t&1);
      float s=0.f;
      for (int e2=0;e2<32;e2++) s += SVC[i*256+h2*32+e2]*Wo[i*65536+(h2*32+e2)*256+c];
      UT[(i*8+h2)*256+c]=s;
    }
    if (t>=32 && t<64){
      int u=t-32, i=u>>4, h2=(u>>1)&7, e=c0+(u&1);
      float s=0.f;
      for (int c2=0;c2<32;c2++) s += Wq[i*65536+e*256+h2*32+c2]*SKC[i*256+h2*32+c2];
      KAP[(i*8+h2)*256+e]=s;
    }
    if (g==0 && t>=64 && t<80){
      int u=t-64, i=u>>3, h2=u&7;
      float s=0.f;
      for (int c2=0;c2<32;c2++) s += bq[i*256+h2*32+c2]*SKC[i*256+h2*32+c2];
      BETA[i*8+h2]=s;
    }
  }
  gbar_f(ARR,REL,++ep);

  // ================= Pre-loop: A for row 0, mask 1 (WG 0) =================
  if (g==0){
    float* axr=sm; float* arr=sm+256; float* am8=sm+512; float* ard=sm+528;
    axr[t]=ld_c(&Yg[t]);
    __syncthreads();
    a_chain(axr,arr,am8,ard, KAP,BETA,WVEC,CC,UT,lng,lnb, 1, t);
    st_c(&R1[t], arr[t]);
  }
  gbar_f(ARR,REL,++ep);

  // =========================== MASTER (WG 128) =============================
  if (g == NWRK){
    for (int tok=1; tok<64; tok++){
      for (int b=0;b<3;b++){
        ++ep;
        if (t < NWRK){ while (ld_fi(ARR + t*16) != ep) {} }   // tight pre-spin
        __syncthreads();
        if (t < NWRK) st_fi(RELV + t*16, ep);
        __syncthreads();
      }
      ++ep;
      if (t < NWRK){ while (ld_fi(ARR + t*16) != ep) {} }
      __syncthreads();
      ull k = 0ull;
      if (t < NWRK) k = ld_u64(KEY + t*8);
#pragma unroll
      for (int m=32;m;m>>=1){
        ull o=shflx64(k,m);
        k = (o>k)? o : k;
      }
      if ((t&63)==0 && t<NWRK) redU[t>>6]=k;
      __syncthreads();
      if (t==0){
        ull kk=redU[0];
        if (redU[1]>kk) kk=redU[1];
        wms = (int)(~(unsigned int)(kk & 0xffffffffull));
      }
      __syncthreads();
      if (t < NWRK) st_fi(RELV2 + t*16, (ep<<14) | wms);
      __syncthreads();
    }
    return;
  }

  // =========================== WORKERS (WGs 0..127) ========================
  const int h  = g&7;
  const int rg = g>>3;

  for (int tok=1; tok<64; tok++){
    const int n = tok-1;

    // ---- Stage B: [redundant A for row n, token from winS] + self0 QKV proj ----
    {
      float* rows4 = sm; // [4][256]
#pragma unroll
      for (int jj=0;jj<4;jj++) rows4[jj*256+t] = ld_c(&R1[(rg+16*jj)*256+t]);
      if (tok>1 && rg==(n&15)){
        float* axr=sm+2700; float* arr2=sm+2956; float* am8=sm+3212; float* ard=sm+3224;
        int v = winS;                    // broadcast by previous winner-barrier
        if (h==0 && t==0) out[n]=v;
        axr[t] = emb[v*256+t] + pe_val(n,t);
        if (h==0) st_c(&Yg[n*256+t], axr[t]);
        __syncthreads();
        a_chain(axr,arr2,am8,ard, KAP,BETA,WVEC,CC,UT,lng,lnb, tok, t);
        rows4[(n>>4)*256+t] = arr2[t];
        if (h==0) st_c(&R1[n*256+t], arr2[t]);
      }
      __syncthreads();
      int c=t&31, epp=t>>5;
      const int col=h*32+c;
      float aq[4]={0,0,0,0}, ak[4]={0,0,0,0}, av[4]={0,0,0,0};
#pragma unroll 8
      for (int e=epp*32; e<epp*32+32; e++){
        float wq_=Wq[e*256+col], wk_=Wk[e*256+col], wv_=Wv[e*256+col];
#pragma unroll
        for (int jj=0;jj<4;jj++){ float r=rows4[jj*256+e]; aq[jj]+=r*wq_; ak[jj]+=r*wk_; av[jj]+=r*wv_; }
      }
#pragma unroll
      for (int jj=0;jj<4;jj++){
        aq[jj]+=__shfl_xor(aq[jj],32,64);
        ak[jj]+=__shfl_xor(ak[jj],32,64);
        av[jj]+=__shfl_xor(av[jj],32,64);
      }
      float4* redq=(float4*)(sm+1056); float4* redk=(float4*)(sm+1568); float4* redv4=(float4*)(sm+2080);
      int lane=t&63, wid=t>>6;
      if (lane<32){
        redq[wid*32+lane]=make_float4(aq[0],aq[1],aq[2],aq[3]);
        redk[wid*32+lane]=make_float4(ak[0],ak[1],ak[2],ak[3]);
        redv4[wid*32+lane]=make_float4(av[0],av[1],av[2],av[3]);
      }
      __syncthreads();
      if (t<32){
        float4 A=redq[t],B4=redq[32+t],C4=redq[64+t],D4=redq[96+t];
        float sq[4]={A.x+B4.x+C4.x+D4.x, A.y+B4.y+C4.y+D4.y, A.z+B4.z+C4.z+D4.z, A.w+B4.w+C4.w+D4.w};
        A=redk[t];B4=redk[32+t];C4=redk[64+t];D4=redk[96+t];
        float sk[4]={A.x+B4.x+C4.x+D4.x, A.y+B4.y+C4.y+D4.y, A.z+B4.z+C4.z+D4.z, A.w+B4.w+C4.w+D4.w};
        A=redv4[t];B4=redv4[32+t];C4=redv4[64+t];D4=redv4[96+t];
        float sv[4]={A.x+B4.x+C4.x+D4.x, A.y+B4.y+C4.y+D4.y, A.z+B4.z+C4.z+D4.z, A.w+B4.w+C4.w+D4.w};
        int cc=h*32+t;
        float bq_=bq[cc], bk_=bk[cc], bv_=bv[cc];
#pragma unroll
        for (int jj=0;jj<4;jj++){
          int q_=rg+16*jj;
          if (q_<tok){
            st_c(&QB[q_*256+cc], sq[jj]+bq_);
            st_c(&KB[q_*256+cc], sk[jj]+bk_);
            st_c(&VB[q_*256+cc], sv[jj]+bv_);
          }
        }
      }
    }
    gbar_w(ARR,RELV,++ep);

    // ---- Stage C: self0 attention + per-head partial O-proj -> Z2P ----
    {
      float* Ks=sm; float* Vs=sm+2112; float* qrow=sm+4224; float* arow=sm+4352; float* o2s=sm+4608;
      int k=t>>2, f0=(t&3)*8;
      if (k<tok){
        const ull* KBp = (const ull*)(KB + k*256 + h*32 + f0);
        const ull* VBp = (const ull*)(VB + k*256 + h*32 + f0);
        ull kb[4], vb[4];
#pragma unroll
        for (int i2=0;i2<4;i2++){ kb[i2]=ld_u64(KBp+i2); vb[i2]=ld_u64(VBp+i2); }
#pragma unroll
        for (int i2=0;i2<4;i2++){
          Ks[k*33+f0+2*i2]   = __uint_as_float((unsigned)kb[i2]);
          Ks[k*33+f0+2*i2+1] = __uint_as_float((unsigned)(kb[i2]>>32));
          Vs[k*33+f0+2*i2]   = __uint_as_float((unsigned)vb[i2]);
          Vs[k*33+f0+2*i2+1] = __uint_as_float((unsigned)(vb[i2]>>32));
        }
      }
      if (t<128){ int jj=t>>5, c=t&31; int q_=rg+16*jj; if (q_<tok) qrow[jj*32+c]=ld_c(&QB[q_*256+h*32+c]); }
      __syncthreads();
      int w=t>>6, lane=t&63; int q_=rg+16*w; bool ok=q_<tok;
      float sc=-3.4e38f;
      if (ok && lane<tok){
        sc=0.f;
#pragma unroll
        for (int c2=0;c2<32;c2++) sc+=qrow[w*32+c2]*Ks[lane*33+c2];
        sc*=ISQ;
      }
      float mx=wredmax(sc);
      float ex=(ok&&lane<tok)? expf(sc-mx):0.f;
      float sd=wredsum(ex);
      arow[w*64+lane]= ok ? ex/sd : 0.f;
      __syncthreads();
      int j=lane&31, half=lane>>5;
      float oa=0.f;
      if (ok){ for (int k2=half;k2<tok;k2+=2) oa+=arow[w*64+k2]*Vs[k2*33+j]; }
      oa += __shfl_xor(oa,32,64);
      if (lane<32) o2s[w*32+j]=oa;
      __syncthreads();
      float acc[4]={0,0,0,0};
#pragma unroll 8
      for (int j2=0;j2<32;j2++){
        float wv_=Wo[(h*32+j2)*256+t];
#pragma unroll
        for (int jj=0;jj<4;jj++) acc[jj]+=o2s[jj*32+j2]*wv_;
      }
#pragma unroll
      for (int jj=0;jj<4;jj++){ int q2=rg+16*jj; if (q2<tok) st_c(&Z2P[(h*64+q2)*256+t], acc[jj]); }
    }
    gbar_w(ARR,RELV,++ep);

    // ---- Stage E: z2 assemble + LN -> r2 ; self1 K/V proj (+Q for row n) ----
    {
      float* rows4=sm; float* mus=sm+1024;
#pragma unroll
      for (int jj=0;jj<4;jj++){
        int q_=rg+16*jj;
        float z = bo[t] + ld_c(&R1[q_*256+t]);
#pragma unroll
        for (int h2=0;h2<8;h2++) z += ld_c(&Z2P[(h2*64+q_)*256+t]);
        rows4[jj*256+t]=z;
      }
      __syncthreads();
      {
        int w=t>>6, lane=t&63;
        float v0=rows4[w*256+lane], v1=rows4[w*256+64+lane], v2=rows4[w*256+128+lane], v3=rows4[w*256+192+lane];
        float s=v0+v1+v2+v3, sq2=v0*v0+v1*v1+v2*v2+v3*v3;
        s=wredsum(s); sq2=wredsum(sq2);
        if (lane==0){
          float mu=s*(1.f/256.f);
          float var=sq2*(1.f/256.f)-mu*mu;
          mus[w*2]=mu; mus[w*2+1]=1.f/sqrtf(var+1e-5f);
        }
      }
      __syncthreads();
#pragma unroll
      for (int jj=0;jj<4;jj++){
        float mu=mus[jj*2], rstd=mus[jj*2+1];
        float val=(rows4[jj*256+t]-mu)*rstd*lng[t]+lnb[t];
        rows4[jj*256+t]=val;
        int q_=rg+16*jj;
        if (h==0 && q_==n) st_c(&R2[q_*256+t], val);
      }
      __syncthreads();
      int c=t&31, epp=t>>5;
      const int col=h*32+c;
      float aq[4]={0,0,0,0}, ak[4]={0,0,0,0}, av[4]={0,0,0,0};
#pragma unroll 8
      for (int e=epp*32; e<epp*32+32; e++){
        float wq_=Wq[65536+e*256+col], wk_=Wk[65536+e*256+col], wv_=Wv[65536+e*256+col];
#pragma unroll
        for (int jj=0;jj<4;jj++){ float r=rows4[jj*256+e]; aq[jj]+=r*wq_; ak[jj]+=r*wk_; av[jj]+=r*wv_; }
      }
#pragma unroll
      for (int jj=0;jj<4;jj++){
        aq[jj]+=__shfl_xor(aq[jj],32,64);
        ak[jj]+=__shfl_xor(ak[jj],32,64);
        av[jj]+=__shfl_xor(av[jj],32,64);
      }
      float4* redq=(float4*)(sm+1056); float4* redk=(float4*)(sm+1568); float4* redv4=(float4*)(sm+2080);
      int lane=t&63, wid=t>>6;
      if (lane<32){
        redq[wid*32+lane]=make_float4(aq[0],aq[1],aq[2],aq[3]);
        redk[wid*32+lane]=make_float4(ak[0],ak[1],ak[2],ak[3]);
        redv4[wid*32+lane]=make_float4(av[0],av[1],av[2],av[3]);
      }
      __syncthreads();
      if (t<32){
        float4 A=redq[t],B4=redq[32+t],C4=redq[64+t],D4=redq[96+t];
        float sq[4]={A.x+B4.x+C4.x+D4.x, A.y+B4.y+C4.y+D4.y, A.z+B4.z+C4.z+D4.z, A.w+B4.w+C4.w+D4.w};
        A=redk[t];B4=redk[32+t];C4=redk[64+t];D4=redk[96+t];
        float sk[4]={A.x+B4.x+C4.x+D4.x, A.y+B4.y+C4.y+D4.y, A.z+B4.z+C4.z+D4.z, A.w+B4.w+C4.w+D4.w};
        A=redv4[t];B4=redv4[32+t];C4=redv4[64+t];D4=redv4[96+t];
        float sv[4]={A.x+B4.x+C4.x+D4.x, A.y+B4.y+C4.y+D4.y, A.z+B4.z+C4.z+D4.z, A.w+B4.w+C4.w+D4.w};
        int cc=h*32+t;
#pragma unroll
        for (int jj=0;jj<4;jj++){
          int q_=rg+16*jj;
          if (q_<tok){
            st_c(&KB[q_*256+cc], sk[jj]+bk[256+cc]);
            st_c(&VB[q_*256+cc], sv[jj]+bv[256+cc]);
            if (q_==n) st_c(&QB[q_*256+cc], sq[jj]+bq[256+cc]);
          }
        }
      }
    }
    gbar_w(ARR,RELV,++ep);

    // ---- Stage H': F (WGs 0..7) || A-next (WGs 64..126) ; all: mini, logits ----
    {
      float resid = ld_c(&R2[n*256+t]);   // early issue; valid after E-barrier
      if (g < 8){
        const int hh = g;
        float* Ks=sm; float* Vs=sm+2112; float* qn=sm+4224; float* arow=sm+4352; float* o3s=sm+4608;
        int k=t>>2, f0=(t&3)*8;
        if (k<tok){
          const ull* KBp = (const ull*)(KB + k*256 + hh*32 + f0);
          const ull* VBp = (const ull*)(VB + k*256 + hh*32 + f0);
          ull kb[4], vb[4];
#pragma unroll
          for (int i2=0;i2<4;i2++){ kb[i2]=ld_u64(KBp+i2); vb[i2]=ld_u64(VBp+i2); }
#pragma unroll
          for (int i2=0;i2<4;i2++){
            Ks[k*33+f0+2*i2]   = __uint_as_float((unsigned)kb[i2]);
            Ks[k*33+f0+2*i2+1] = __uint_as_float((unsigned)(kb[i2]>>32));
            Vs[k*33+f0+2*i2]   = __uint_as_float((unsigned)vb[i2]);
            Vs[k*33+f0+2*i2+1] = __uint_as_float((unsigned)(vb[i2]>>32));
          }
        }
        if (t<32) qn[t]=ld_c(&QB[n*256+hh*32+t]);
        __syncthreads();
        int lane=t&63, w=t>>6;
        if (w==0){
          float sc=-3.4e38f;
          if (lane<tok){
            sc=0.f;
#pragma unroll
            for (int c2=0;c2<32;c2++) sc+=qn[c2]*Ks[lane*33+c2];
            sc*=ISQ;
          }
          float mx=wredmax(sc);
          float ex=(lane<tok)? expf(sc-mx):0.f;
          float sd=wredsum(ex);
          arow[lane]=ex/sd;
        }
        __syncthreads();
        if (w==0){
          int j=lane&31, half=lane>>5;
          float oa=0.f;
          for (int k2=half;k2<tok;k2+=2) oa+=arow[k2]*Vs[k2*33+j];
          oa+=__shfl_xor(oa,32,64);
          if (lane<32) o3s[j]=oa;
        }
        __syncthreads();
        float acc=0.f;
#pragma unroll 8
        for (int j2=0;j2<32;j2++) acc+=o3s[j2]*Wo[65536+(hh*32+j2)*256+t];
        st_c(&Z3P[hh*256+t], acc);
        __syncthreads();            // drain Z3P stores to LLC
        if (t < NWRK) st_fi(Z3F2 + (hh*NWRK + t)*16, tok);
      } else if (g>=64 && g<127){
        const int q = g-64;
        if (q < tok && tok < 63){
          float* axr=sm; float* arr2=sm+256; float* am8=sm+512; float* ard=sm+528;
          axr[t]=ld_c(&Yg[q*256+t]);
          __syncthreads();
          a_chain(axr,arr2,am8,ard, KAP,BETA,WVEC,CC,UT,lng,lnb, tok+1, t);
          st_c(&R1[q*256+t], arr2[t]);
        }
      }
      // mini-barrier: poll OWN 8 per-consumer flag lines (monotone = tok)
      if (t<8){ while (ld_fi(Z3F2 + (t*NWRK + g)*16) < tok) __builtin_amdgcn_s_sleep(1); }
      __syncthreads();
      // folded-LN logits: GEMV on RAW z; one sync total
      float* outn=sm; float* redv=sm+256; float* pp=sm+512;
      float z = bo[256+t] + resid;
#pragma unroll
      for (int h2=0;h2<8;h2++) z += ld_c(&Z3P[h2*256+t]);
      outn[t]=z;                       // raw z for the GEMV
      float s=wredsum(z), sq2=wredsum(z*z);
      int lane=t&63, wid=t>>6;
      if (lane==0){ redv[wid]=s; redv[4+wid]=sq2; }
      __syncthreads();
      float ts=redv[0]+redv[1]+redv[2]+redv[3];
      float tq=redv[4]+redv[5]+redv[6]+redv[7];
      float mu=ts*(1.f/256.f);
      float var=tq*(1.f/256.f)-mu*mu;
      float rstd=1.f/sqrtf(var+1e-5f);
      const int c = t & 127, half = t >> 7;
      float acc = 0.f;
      if (c < 125){
        const int e0 = half*128;
#pragma unroll 8
        for (int e=e0; e<e0+128; e++) acc += outn[e]*swl[e*128+c];
      }
      if (half==1 && c<125) pp[c]=acc;
      __syncthreads();
      ull key=0ull;
      if (half==0 && c<125){
        int v=g*125+c;
        float a2 = rstd*(acc + pp[c] - mu*S1s[c]) + CONSTs[c];
        unsigned int fb=__float_as_uint(a2);
        fb = (fb&0x80000000u)? ~fb : (fb|0x80000000u);
        key=(((ull)fb)<<32) | (ull)(~(unsigned int)v);
      }
#pragma unroll
      for (int m=32;m;m>>=1){
        ull o=shflx64(key,m);
        key = (o>key)? o : key;
      }
      if (lane==0) redU[wid]=key;
      __syncthreads();
      if (t==0){
        ull kk=redU[0];
        if (redU[1]>kk) kk=redU[1];
        if (redU[2]>kk) kk=redU[2];
        if (redU[3]>kk) kk=redU[3];
        st_u64(KEY + g*8, kk);       // private line; no contention
      }
    }
    // ---- winner-barrier (worker side): arrive; poll own payload line ----
    {
      ++ep;
      __syncthreads();   // drains KEY store + all sc1 stage stores
      if (t==0){
        st_fi(ARR + g*16, ep);
        int r;
        while (((r = ld_fi(RELV2 + g*16)) >> 14) != ep) __builtin_amdgcn_s_sleep(1);
        winS = r & 0x3fff;
      }
      __syncthreads();
    }
  }

  // epilogue: final winner (broadcast by the last winner-barrier)
  if (g==0 && t==0) out[63] = winS;
}

extern "C" void kernel_launch(void* const* d_in, const int* in_sizes, int n_in,
                              void* d_out, int out_size, void* d_ws, size_t ws_size,
                              hipStream_t stream)
{
  (void)in_sizes; (void)n_in; (void)out_size; (void)ws_size;
  hipLaunchKernelGGL(gen18124_kernel, dim3(NWG), dim3(NT), 131072, stream,
    (const float*)d_in[0],  (const float*)d_in[1],  (const float*)d_in[2],
    (const float*)d_in[3],  (const float*)d_in[4],  (const float*)d_in[5],
    (const float*)d_in[6],  (const float*)d_in[7],  (const float*)d_in[8],
    (const float*)d_in[9],  (const float*)d_in[10], (const float*)d_in[11],
    (const float*)d_in[12], (const float*)d_in[13], (const float*)d_in[14],
    (const float*)d_in[15], (int*)d_out, (float*)d_ws);
}

// Round 14
// 3450.858 us; speedup vs baseline: 1.1736x; 1.0321x over previous
//
#include <hip/hip_runtime.h>
#include <stdint.h>

// R17 = R16 (best: 3484us steady) + head/tail serial-chain compression:
//  R16 post-mortem: stage head/tail serial work is FULLY on the critical path
//  (paired loads + tail trim gave -6.8us/iter, 6x prediction). Next targets:
//  (1) B-tail: t<32 x (12 LDS loads + 12 agent stores) -> t<128 x (12 scalar
//      LDS loads + 3 stores). 4x parallel write-out. Same FP add order.
//  (2) E-tail: same restructure.
//  (3) UTT[256][16] transposed copy of UT: a_chain's 8 strided global loads
//      -> 2 aligned float4 loads; z updates stay sequential += (bit-exact).
//  Everything else identical to R16.

#define NWG 129
#define NWRK 128
#define NT 256

typedef unsigned long long ull;

__device__ __forceinline__ float ld_c(const float* p){
  return __hip_atomic_load(p, __ATOMIC_RELAXED, __HIP_MEMORY_SCOPE_AGENT);
}
__device__ __forceinline__ void st_c(float* p, float v){
  __hip_atomic_store(p, v, __ATOMIC_RELAXED, __HIP_MEMORY_SCOPE_AGENT);
}
__device__ __forceinline__ int ld_fi(const int* p){
  return __hip_atomic_load(p, __ATOMIC_RELAXED, __HIP_MEMORY_SCOPE_AGENT);
}
__device__ __forceinline__ void st_fi(int* p, int v){
  __hip_atomic_store(p, v, __ATOMIC_RELAXED, __HIP_MEMORY_SCOPE_AGENT);
}
__device__ __forceinline__ ull ld_u64(const ull* p){
  return __hip_atomic_load(p, __ATOMIC_RELAXED, __HIP_MEMORY_SCOPE_AGENT);
}
__device__ __forceinline__ void st_u64(ull* p, ull v){
  __hip_atomic_store(p, v, __ATOMIC_RELAXED, __HIP_MEMORY_SCOPE_AGENT);
}

__device__ __forceinline__ float wredsum(float v){
#pragma unroll
  for (int m=32;m;m>>=1) v += __shfl_xor(v,m,64);
  return v;
}
__device__ __forceinline__ float wredmax(float v){
#pragma unroll
  for (int m=32;m;m>>=1) v = fmaxf(v,__shfl_xor(v,m,64));
  return v;
}
__device__ __forceinline__ float g32sum(float v){
#pragma unroll
  for (int m=16;m;m>>=1) v += __shfl_xor(v,m,64);
  return v;
}
__device__ __forceinline__ float g32max(float v){
#pragma unroll
  for (int m=16;m;m>>=1) v = fmaxf(v,__shfl_xor(v,m,64));
  return v;
}
__device__ __forceinline__ ull shflx64(ull v,int m){
  unsigned int lo=(unsigned int)(v&0xffffffffull), hi=(unsigned int)(v>>32);
  lo=__shfl_xor(lo,m,64); hi=__shfl_xor(hi,m,64);
  return (((ull)hi)<<32)|(ull)lo;
}

__device__ __forceinline__ float pe_val(int l, int e){
  int j = e >> 1;
  float dv = expf((float)(2*j) * (-0.035977892078031970f));
  float arg = (float)l * dv;
  return (e & 1) ? cosf(arg) : sinf(arg);
}

// A-chain: cross blocks x2 (rank-1 collapsed) + LN -> rrow. WG-uniform.
// UTT: [256][16] transposed tables; 2 float4 loads replace 8 strided loads.
__device__ __forceinline__ void a_chain(const float* xrow, float* rrow,
    float* m8, float* redv,
    const float* KAP, const float* BETA, const float* WVEC,
    const float* CC, const float* UTT,
    const float* lng, const float* lnb, int tokm, int t){
  const float ISQ = 0.17677669529663687f;
  for (int blk=0; blk<2; blk++){
    const float* src = blk ? rrow : xrow;
    int hh=t>>5, j=t&31;
    float part=0.f;
    for (int jj=j; jj<256; jj+=32) part += src[jj]*KAP[(blk*8+hh)*256+jj];
    part = g32sum(part);
    float alpha = (part + BETA[blk*8+hh]) * ISQ;
    float s1 = (j<tokm)     ? alpha*WVEC[j]    : -3.4e38f;
    float s2 = (j+32<tokm)  ? alpha*WVEC[j+32] : -3.4e38f;
    float mx = g32max(fmaxf(s1,s2));
    float e1 = expf(s1-mx), e2 = expf(s2-mx);
    float sn = e1*((j<tokm)?WVEC[j]:0.f) + e2*((j+32<tokm)?WVEC[j+32]:0.f);
    float sd = e1+e2;
    sn=g32sum(sn); sd=g32sum(sd);
    if (j==0) m8[hh]=sn/sd;
    __syncthreads();
    float x_ = blk ? rrow[t] : xrow[t];
    float z = CC[blk*256+t] + x_;
    {
      const float4* up = (const float4*)(UTT + (t<<4) + blk*8);
      float4 ua = up[0], ub = up[1];
      z += m8[0]*ua.x; z += m8[1]*ua.y; z += m8[2]*ua.z; z += m8[3]*ua.w;
      z += m8[4]*ub.x; z += m8[5]*ub.y; z += m8[6]*ub.z; z += m8[7]*ub.w;
    }
    float ssum=wredsum(z), ssq=wredsum(z*z);
    int lane=t&63, wid=t>>6;
    if (lane==0){ redv[wid]=ssum; redv[4+wid]=ssq; }
    __syncthreads();
    float ts=redv[0]+redv[1]+redv[2]+redv[3];
    float tq=redv[4]+redv[5]+redv[6]+redv[7];
    float mu=ts*(1.f/256.f);
    float var=tq*(1.f/256.f)-mu*mu;
    float rstd=1.f/sqrtf(var+1e-5f);
    float rv=(z-mu)*rstd*lng[blk*256+t]+lnb[blk*256+t];
    __syncthreads();
    rrow[t]=rv;
    __syncthreads();
  }
}

// fenced barrier (prelude only): WG0 master over NWG=129 arrivals
__device__ __forceinline__ void gbar_f(int* arr, int* rel, int ep){
  __syncthreads();
  if (threadIdx.x==0){
    __builtin_amdgcn_fence(__ATOMIC_RELEASE, "agent");
    __hip_atomic_store(arr + blockIdx.x*16, ep, __ATOMIC_RELAXED, __HIP_MEMORY_SCOPE_AGENT);
  }
  if (blockIdx.x==0){
    if (threadIdx.x < NWG){
      while (__hip_atomic_load(arr + threadIdx.x*16, __ATOMIC_RELAXED, __HIP_MEMORY_SCOPE_AGENT) != ep)
        __builtin_amdgcn_s_sleep(1);
    }
    __syncthreads();
    if (threadIdx.x==0)
      __hip_atomic_store(rel, ep, __ATOMIC_RELAXED, __HIP_MEMORY_SCOPE_AGENT);
  }
  if (threadIdx.x==0){
    while (__hip_atomic_load(rel, __ATOMIC_RELAXED, __HIP_MEMORY_SCOPE_AGENT) != ep)
      __builtin_amdgcn_s_sleep(1);
    __builtin_amdgcn_fence(__ATOMIC_ACQUIRE, "agent");
  }
  __syncthreads();
}

// worker loop barrier: arrive + poll own release line (master is WG128)
__device__ __forceinline__ void gbar_w(int* arr, int* relv, int ep){
  __syncthreads();   // drains vmcnt: sc1 stores LLC-visible before arrive
  if (threadIdx.x==0){
    st_fi(arr + blockIdx.x*16, ep);
    while (ld_fi(relv + blockIdx.x*16) != ep) __builtin_amdgcn_s_sleep(1);
  }
  __syncthreads();
}

extern "C" __global__ __launch_bounds__(256, 2)
void gen18124_kernel(const float* __restrict__ noise,
                     const float* __restrict__ iw, const float* __restrict__ ib,
                     const float* __restrict__ Wq, const float* __restrict__ bq,
                     const float* __restrict__ Wk, const float* __restrict__ bk,
                     const float* __restrict__ Wv, const float* __restrict__ bv,
                     const float* __restrict__ Wo, const float* __restrict__ bo,
                     const float* __restrict__ lng, const float* __restrict__ lnb,
                     const float* __restrict__ emb, const float* __restrict__ sw,
                     const float* __restrict__ sb,
                     int* __restrict__ out, float* __restrict__ ws)
{
  const float ISQ = 0.17677669529663687f; // 1/sqrt(32)
  __shared__ float sm[5376];
  __shared__ float S1s[128];     // per-col sum of folded weights (own 125 cols)
  __shared__ float CONSTs[128];  // per-col lnb-fold + sb
  __shared__ ull redU[4];
  __shared__ int winS;
  __shared__ int wms;
  extern __shared__ float swl[]; // [256][128] lng2-FOLDED soft_W slice, 128KB

  // ---- workspace layout (floats) ----
  float* WVEC = ws;            // 64
  float* SKC  = ws+64;         // [2][256]
  float* SVC  = ws+576;        // [2][256]
  float* KAP  = ws+1088;       // [2][8][256]
  float* UT   = ws+5184;       // [2][8][256]
  float* CC   = ws+9280;       // [2][256]
  float* BETA = ws+9792;       // [2][8]
  int* ARR = (int*)(ws+10080); // 129*16 ints (arrive lines; ends 12144)
  int* REL = (int*)(ws+12144); // prelude single release line (16)
  ull* KEY = (ull*)(ws+12160); // 128 entries, stride 8 ull; ends 14208
  float* Yg  = ws+14208;       // [64][256]
  float* R1  = ws+30592;       // [64][256]
  float* QB  = ws+46976;       // [64][256]
  float* KB  = ws+63360;       // [64][256]
  float* VB  = ws+79744;       // [64][256]
  float* R2  = ws+96128;       // [64][256]
  float* Z2P = ws+112512;      // [8][64][256]
  float* Z3P = ws+243584;      // [8][256]   ends 245632
  int* RELV  = (int*)(ws+245632); // 128*16 per-WG loop release lines
  int* RELV2 = (int*)(ws+247680); // 128*16 per-WG winner release lines (payload)
  int* Z3F2  = (int*)(ws+249728); // [8][128]*16 fan-out mini flags; ends 266112
  float* UTT = ws+266112;      // [256][16] transposed UT; ends 270208

  const int g = blockIdx.x, t = threadIdx.x;
  int ep = 0;

  // ---- soft_W slice -> LDS, folded with lng2 (workers only) ----
  if (g < NWRK){
    const int base = g*125;
#pragma unroll 8
    for (int i=t; i<256*128; i+=NT){
      int e=i>>7, c=i&127;
      float val = 0.f;
      if (c<125) val = lng[256+e]*sw[e*16000 + base + c];
      swl[i]=val;
    }
    __syncthreads();
    // per-col S1 (sum of folded weights) + CONST (lnb fold + sb)
    if (t < 128){
      float s1v=0.f, cov=0.f;
      if (t < 125){
        const int col = base + t;
        for (int e=0;e<256;e++){
          s1v += swl[e*128+t];
          cov += lnb[256+e]*sw[e*16000+col];
        }
        cov += sb[col];
      }
      S1s[t]=s1v; CONSTs[t]=cov;
    }
  }

  // ================= Prelude A: colsums, wvec, Y0, init (workers) ==========
  if (g < NWRK){
    __syncthreads();
    int c0 = 2*g;
    float a0=Wk[t*256+c0],       a1=Wk[t*256+c0+1];
    float a2=Wk[65536+t*256+c0], a3=Wk[65536+t*256+c0+1];
    float a4=Wv[t*256+c0],       a5=Wv[t*256+c0+1];
    float a6=Wv[65536+t*256+c0], a7=Wv[65536+t*256+c0+1];
    a0=wredsum(a0); a1=wredsum(a1); a2=wredsum(a2); a3=wredsum(a3);
    a4=wredsum(a4); a5=wredsum(a5); a6=wredsum(a6); a7=wredsum(a7);
    int lane=t&63, wid=t>>6;
    if (lane==0){
      sm[wid*8+0]=a0; sm[wid*8+1]=a1; sm[wid*8+2]=a2; sm[wid*8+3]=a3;
      sm[wid*8+4]=a4; sm[wid*8+5]=a5; sm[wid*8+6]=a6; sm[wid*8+7]=a7;
    }
    __syncthreads();
    if (t<8){
      float s=sm[t]+sm[8+t]+sm[16+t]+sm[24+t];
      if (t<4) SKC[(t>>1)*256 + c0 + (t&1)] = s;
      else     SVC[((t-4)>>1)*256 + c0 + ((t-4)&1)] = s;
    }
    __syncthreads();
    if (g==0){
      // zero the monotone fan-out flags (Z3F2 uses < tok compares)
      for (int i=t;i<16384;i+=NT) Z3F2[i]=0;
      float* wl = sm+64;
      if (t<64) wl[t] = noise[t];
      __syncthreads();
      for (int i=0;i<4;i++){
        float acc=0.f;
        if (t<64){
          for (int in_=0;in_<64;in_++) acc += wl[in_]*iw[(i*64+in_)*64+t];
          acc += ib[i*64+t];
        }
        __syncthreads();
        if (t<64) wl[t]=acc;
        __syncthreads();
      }
      if (t<64) WVEC[t]=wl[t];
    }
    if (g==1){
      Yg[t] = emb[t] + pe_val(0,t);
      if (t==0) out[0]=0;
    }
  }
  gbar_f(ARR,REL,++ep);

  // ================= Prelude B: KAP / UT+UTT / CC / BETA tables (workers) ===
  if (g < NWRK){
    int c0 = 2*g;
    float p00 = bv[t]    *Wo[t*256+c0],        p01 = bv[t]    *Wo[t*256+c0+1];
    float p10 = bv[256+t]*Wo[65536+t*256+c0],  p11 = bv[256+t]*Wo[65536+t*256+c0+1];
    p00=wredsum(p00); p01=wredsum(p01); p10=wredsum(p10); p11=wredsum(p11);
    int lane=t&63, wid=t>>6;
    if (lane==0){ sm[wid*4+0]=p00; sm[wid*4+1]=p01; sm[wid*4+2]=p10; sm[wid*4+3]=p11; }
    __syncthreads();
    if (t<4){
      float s=sm[t]+sm[4+t]+sm[8+t]+sm[12+t];
      int i=t>>1, cl=t&1;
      CC[i*256+c0+cl] = s + bo[i*256+c0+cl];
    }
    if (t<32){
      int i=t>>4, h2=(t>>1)&7, c=c0+(t&1);
      float s=0.f;
      for (int e2=0;e2<32;e2++) s += SVC[i*256+h2*32+e2]*Wo[i*65536+(h2*32+e2)*256+c];
      UT[(i*8+h2)*256+c]=s;
      UTT[c*16 + i*8+h2]=s;    // transposed copy for a_chain paired loads
    }
    if (t>=32 && t<64){
      int u=t-32, i=u>>4, h2=(u>>1)&7, e=c0+(u&1);
      float s=0.f;
      for (int c2=0;c2<32;c2++) s += Wq[i*65536+e*256+h2*32+c2]*SKC[i*256+h2*32+c2];
      KAP[(i*8+h2)*256+e]=s;
    }
    if (g==0 && t>=64 && t<80){
      int u=t-64, i=u>>3, h2=u&7;
      float s=0.f;
      for (int c2=0;c2<32;c2++) s += bq[i*256+h2*32+c2]*SKC[i*256+h2*32+c2];
      BETA[i*8+h2]=s;
    }
  }
  gbar_f(ARR,REL,++ep);

  // ================= Pre-loop: A for row 0, mask 1 (WG 0) =================
  if (g==0){
    float* axr=sm; float* arr=sm+256; float* am8=sm+512; float* ard=sm+528;
    axr[t]=ld_c(&Yg[t]);
    __syncthreads();
    a_chain(axr,arr,am8,ard, KAP,BETA,WVEC,CC,UTT,lng,lnb, 1, t);
    st_c(&R1[t], arr[t]);
  }
  gbar_f(ARR,REL,++ep);

  // =========================== MASTER (WG 128) =============================
  if (g == NWRK){
    for (int tok=1; tok<64; tok++){
      for (int b=0;b<3;b++){
        ++ep;
        if (t < NWRK){ while (ld_fi(ARR + t*16) != ep) {} }   // tight pre-spin
        __syncthreads();
        if (t < NWRK) st_fi(RELV + t*16, ep);
        __syncthreads();
      }
      ++ep;
      if (t < NWRK){ while (ld_fi(ARR + t*16) != ep) {} }
      __syncthreads();
      ull k = 0ull;
      if (t < NWRK) k = ld_u64(KEY + t*8);
#pragma unroll
      for (int m=32;m;m>>=1){
        ull o=shflx64(k,m);
        k = (o>k)? o : k;
      }
      if ((t&63)==0 && t<NWRK) redU[t>>6]=k;
      __syncthreads();
      if (t==0){
        ull kk=redU[0];
        if (redU[1]>kk) kk=redU[1];
        wms = (int)(~(unsigned int)(kk & 0xffffffffull));
      }
      __syncthreads();
      if (t < NWRK) st_fi(RELV2 + t*16, (ep<<14) | wms);
      __syncthreads();
    }
    return;
  }

  // =========================== WORKERS (WGs 0..127) ========================
  const int h  = g&7;
  const int rg = g>>3;

  for (int tok=1; tok<64; tok++){
    const int n = tok-1;

    // ---- Stage B: [redundant A for row n, token from winS] + self0 QKV proj ----
    {
      float* rows4 = sm; // [4][256]
#pragma unroll
      for (int jj=0;jj<4;jj++) rows4[jj*256+t] = ld_c(&R1[(rg+16*jj)*256+t]);
      if (tok>1 && rg==(n&15)){
        float* axr=sm+2700; float* arr2=sm+2956; float* am8=sm+3212; float* ard=sm+3224;
        int v = winS;                    // broadcast by previous winner-barrier
        if (h==0 && t==0) out[n]=v;
        axr[t] = emb[v*256+t] + pe_val(n,t);
        if (h==0) st_c(&Yg[n*256+t], axr[t]);
        __syncthreads();
        a_chain(axr,arr2,am8,ard, KAP,BETA,WVEC,CC,UTT,lng,lnb, tok, t);
        rows4[(n>>4)*256+t] = arr2[t];
        if (h==0) st_c(&R1[n*256+t], arr2[t]);
      }
      __syncthreads();
      int c=t&31, epp=t>>5;
      const int col=h*32+c;
      float aq[4]={0,0,0,0}, ak[4]={0,0,0,0}, av[4]={0,0,0,0};
#pragma unroll 8
      for (int e=epp*32; e<epp*32+32; e++){
        float wq_=Wq[e*256+col], wk_=Wk[e*256+col], wv_=Wv[e*256+col];
#pragma unroll
        for (int jj=0;jj<4;jj++){ float r=rows4[jj*256+e]; aq[jj]+=r*wq_; ak[jj]+=r*wk_; av[jj]+=r*wv_; }
      }
#pragma unroll
      for (int jj=0;jj<4;jj++){
        aq[jj]+=__shfl_xor(aq[jj],32,64);
        ak[jj]+=__shfl_xor(ak[jj],32,64);
        av[jj]+=__shfl_xor(av[jj],32,64);
      }
      float4* redq=(float4*)(sm+1056); float4* redk=(float4*)(sm+1568); float4* redv4=(float4*)(sm+2080);
      int lane=t&63, wid=t>>6;
      if (lane<32){
        redq[wid*32+lane]=make_float4(aq[0],aq[1],aq[2],aq[3]);
        redk[wid*32+lane]=make_float4(ak[0],ak[1],ak[2],ak[3]);
        redv4[wid*32+lane]=make_float4(av[0],av[1],av[2],av[3]);
      }
      __syncthreads();
      if (t<128){
        int jj=t>>5, c2=t&31;
        const float* rq = sm+1056; const float* rk = sm+1568; const float* rv2 = sm+2080;
        int off = c2*4 + jj;
        float sq = rq[off] + rq[128+off] + rq[256+off] + rq[384+off];
        float sk = rk[off] + rk[128+off] + rk[256+off] + rk[384+off];
        float sv = rv2[off] + rv2[128+off] + rv2[256+off] + rv2[384+off];
        int cc=h*32+c2;
        int q_=rg+16*jj;
        if (q_<tok){
          st_c(&QB[q_*256+cc], sq+bq[cc]);
          st_c(&KB[q_*256+cc], sk+bk[cc]);
          st_c(&VB[q_*256+cc], sv+bv[cc]);
        }
      }
    }
    gbar_w(ARR,RELV,++ep);

    // ---- Stage C: self0 attention + per-head partial O-proj -> Z2P ----
    {
      float* Ks=sm; float* Vs=sm+2112; float* qrow=sm+4224; float* arow=sm+4352; float* o2s=sm+4608;
      int k=t>>2, f0=(t&3)*8;
      if (k<tok){
        const ull* KBp = (const ull*)(KB + k*256 + h*32 + f0);
        const ull* VBp = (const ull*)(VB + k*256 + h*32 + f0);
        ull kb[4], vb[4];
#pragma unroll
        for (int i2=0;i2<4;i2++){ kb[i2]=ld_u64(KBp+i2); vb[i2]=ld_u64(VBp+i2); }
#pragma unroll
        for (int i2=0;i2<4;i2++){
          Ks[k*33+f0+2*i2]   = __uint_as_float((unsigned)kb[i2]);
          Ks[k*33+f0+2*i2+1] = __uint_as_float((unsigned)(kb[i2]>>32));
          Vs[k*33+f0+2*i2]   = __uint_as_float((unsigned)vb[i2]);
          Vs[k*33+f0+2*i2+1] = __uint_as_float((unsigned)(vb[i2]>>32));
        }
      }
      if (t<128){ int jj=t>>5, c=t&31; int q_=rg+16*jj; if (q_<tok) qrow[jj*32+c]=ld_c(&QB[q_*256+h*32+c]); }
      __syncthreads();
      int w=t>>6, lane=t&63; int q_=rg+16*w; bool ok=q_<tok;
      float sc=-3.4e38f;
      if (ok && lane<tok){
        sc=0.f;
#pragma unroll
        for (int c2=0;c2<32;c2++) sc+=qrow[w*32+c2]*Ks[lane*33+c2];
        sc*=ISQ;
      }
      float mx=wredmax(sc);
      float ex=(ok&&lane<tok)? expf(sc-mx):0.f;
      float sd=wredsum(ex);
      arow[w*64+lane]= ok ? ex/sd : 0.f;
      __syncthreads();
      int j=lane&31, half=lane>>5;
      float oa=0.f;
      if (ok){ for (int k2=half;k2<tok;k2+=2) oa+=arow[w*64+k2]*Vs[k2*33+j]; }
      oa += __shfl_xor(oa,32,64);
      if (lane<32) o2s[w*32+j]=oa;
      __syncthreads();
      float acc[4]={0,0,0,0};
#pragma unroll 8
      for (int j2=0;j2<32;j2++){
        float wv_=Wo[(h*32+j2)*256+t];
#pragma unroll
        for (int jj=0;jj<4;jj++) acc[jj]+=o2s[jj*32+j2]*wv_;
      }
#pragma unroll
      for (int jj=0;jj<4;jj++){ int q2=rg+16*jj; if (q2<tok) st_c(&Z2P[(h*64+q2)*256+t], acc[jj]); }
    }
    gbar_w(ARR,RELV,++ep);

    // ---- Stage E: z2 assemble + LN -> r2 ; self1 K/V proj (+Q for row n) ----
    {
      float* rows4=sm; float* mus=sm+1024;
#pragma unroll
      for (int jj=0;jj<4;jj++){
        int q_=rg+16*jj;
        float z = bo[t] + ld_c(&R1[q_*256+t]);
#pragma unroll
        for (int h2=0;h2<8;h2++) z += ld_c(&Z2P[(h2*64+q_)*256+t]);
        rows4[jj*256+t]=z;
      }
      __syncthreads();
      {
        int w=t>>6, lane=t&63;
        float v0=rows4[w*256+lane], v1=rows4[w*256+64+lane], v2=rows4[w*256+128+lane], v3=rows4[w*256+192+lane];
        float s=v0+v1+v2+v3, sq2=v0*v0+v1*v1+v2*v2+v3*v3;
        s=wredsum(s); sq2=wredsum(sq2);
        if (lane==0){
          float mu=s*(1.f/256.f);
          float var=sq2*(1.f/256.f)-mu*mu;
          mus[w*2]=mu; mus[w*2+1]=1.f/sqrtf(var+1e-5f);
        }
      }
      __syncthreads();
#pragma unroll
      for (int jj=0;jj<4;jj++){
        float mu=mus[jj*2], rstd=mus[jj*2+1];
        float val=(rows4[jj*256+t]-mu)*rstd*lng[t]+lnb[t];
        rows4[jj*256+t]=val;
        int q_=rg+16*jj;
        if (h==0 && q_==n) st_c(&R2[q_*256+t], val);
      }
      __syncthreads();
      int c=t&31, epp=t>>5;
      const int col=h*32+c;
      float aq[4]={0,0,0,0}, ak[4]={0,0,0,0}, av[4]={0,0,0,0};
#pragma unroll 8
      for (int e=epp*32; e<epp*32+32; e++){
        float wq_=Wq[65536+e*256+col], wk_=Wk[65536+e*256+col], wv_=Wv[65536+e*256+col];
#pragma unroll
        for (int jj=0;jj<4;jj++){ float r=rows4[jj*256+e]; aq[jj]+=r*wq_; ak[jj]+=r*wk_; av[jj]+=r*wv_; }
      }
#pragma unroll
      for (int jj=0;jj<4;jj++){
        aq[jj]+=__shfl_xor(aq[jj],32,64);
        ak[jj]+=__shfl_xor(ak[jj],32,64);
        av[jj]+=__shfl_xor(av[jj],32,64);
      }
      float4* redq=(float4*)(sm+1056); float4* redk=(float4*)(sm+1568); float4* redv4=(float4*)(sm+2080);
      int lane=t&63, wid=t>>6;
      if (lane<32){
        redq[wid*32+lane]=make_float4(aq[0],aq[1],aq[2],aq[3]);
        redk[wid*32+lane]=make_float4(ak[0],ak[1],ak[2],ak[3]);
        redv4[wid*32+lane]=make_float4(av[0],av[1],av[2],av[3]);
      }
      __syncthreads();
      if (t<128){
        int jj=t>>5, c2=t&31;
        const float* rq = sm+1056; const float* rk = sm+1568; const float* rv2 = sm+2080;
        int off = c2*4 + jj;
        float sq = rq[off] + rq[128+off] + rq[256+off] + rq[384+off];
        float sk = rk[off] + rk[128+off] + rk[256+off] + rk[384+off];
        float sv = rv2[off] + rv2[128+off] + rv2[256+off] + rv2[384+off];
        int cc=h*32+c2;
        int q_=rg+16*jj;
        if (q_<tok){
          st_c(&KB[q_*256+cc], sk+bk[256+cc]);
          st_c(&VB[q_*256+cc], sv+bv[256+cc]);
          if (q_==n) st_c(&QB[q_*256+cc], sq+bq[256+cc]);
        }
      }
    }
    gbar_w(ARR,RELV,++ep);

    // ---- Stage H': F (WGs 0..7) || A-next (WGs 64..126) ; all: mini, logits ----
    {
      float resid = ld_c(&R2[n*256+t]);   // early issue; valid after E-barrier
      if (g < 8){
        const int hh = g;
        float* Ks=sm; float* Vs=sm+2112; float* qn=sm+4224; float* arow=sm+4352; float* o3s=sm+4608;
        int k=t>>2, f0=(t&3)*8;
        if (k<tok){
          const ull* KBp = (const ull*)(KB + k*256 + hh*32 + f0);
          const ull* VBp = (const ull*)(VB + k*256 + hh*32 + f0);
          ull kb[4], vb[4];
#pragma unroll
          for (int i2=0;i2<4;i2++){ kb[i2]=ld_u64(KBp+i2); vb[i2]=ld_u64(VBp+i2); }
#pragma unroll
          for (int i2=0;i2<4;i2++){
            Ks[k*33+f0+2*i2]   = __uint_as_float((unsigned)kb[i2]);
            Ks[k*33+f0+2*i2+1] = __uint_as_float((unsigned)(kb[i2]>>32));
            Vs[k*33+f0+2*i2]   = __uint_as_float((unsigned)vb[i2]);
            Vs[k*33+f0+2*i2+1] = __uint_as_float((unsigned)(vb[i2]>>32));
          }
        }
        if (t<32) qn[t]=ld_c(&QB[n*256+hh*32+t]);
        __syncthreads();
        int lane=t&63, w=t>>6;
        if (w==0){
          float sc=-3.4e38f;
          if (lane<tok){
            sc=0.f;
#pragma unroll
            for (int c2=0;c2<32;c2++) sc+=qn[c2]*Ks[lane*33+c2];
            sc*=ISQ;
          }
          float mx=wredmax(sc);
          float ex=(lane<tok)? expf(sc-mx):0.f;
          float sd=wredsum(ex);
          arow[lane]=ex/sd;
        }
        __syncthreads();
        if (w==0){
          int j=lane&31, half=lane>>5;
          float oa=0.f;
          for (int k2=half;k2<tok;k2+=2) oa+=arow[k2]*Vs[k2*33+j];
          oa+=__shfl_xor(oa,32,64);
          if (lane<32) o3s[j]=oa;
        }
        __syncthreads();
        float acc=0.f;
#pragma unroll 8
        for (int j2=0;j2<32;j2++) acc+=o3s[j2]*Wo[65536+(hh*32+j2)*256+t];
        st_c(&Z3P[hh*256+t], acc);
        __syncthreads();            // drain Z3P stores to LLC
        if (t < NWRK) st_fi(Z3F2 + (hh*NWRK + t)*16, tok);
      } else if (g>=64 && g<127){
        const int q = g-64;
        if (q < tok && tok < 63){
          float* axr=sm; float* arr2=sm+256; float* am8=sm+512; float* ard=sm+528;
          axr[t]=ld_c(&Yg[q*256+t]);
          __syncthreads();
          a_chain(axr,arr2,am8,ard, KAP,BETA,WVEC,CC,UTT,lng,lnb, tok+1, t);
          st_c(&R1[q*256+t], arr2[t]);
        }
      }
      // mini-barrier: poll OWN 8 per-consumer flag lines (monotone = tok)
      if (t<8){ while (ld_fi(Z3F2 + (t*NWRK + g)*16) < tok) __builtin_amdgcn_s_sleep(1); }
      __syncthreads();
      // folded-LN logits: GEMV on RAW z; one sync total
      float* outn=sm; float* redv=sm+256; float* pp=sm+512;
      float z = bo[256+t] + resid;
#pragma unroll
      for (int h2=0;h2<8;h2++) z += ld_c(&Z3P[h2*256+t]);
      outn[t]=z;                       // raw z for the GEMV
      float s=wredsum(z), sq2=wredsum(z*z);
      int lane=t&63, wid=t>>6;
      if (lane==0){ redv[wid]=s; redv[4+wid]=sq2; }
      __syncthreads();
      float ts=redv[0]+redv[1]+redv[2]+redv[3];
      float tq=redv[4]+redv[5]+redv[6]+redv[7];
      float mu=ts*(1.f/256.f);
      float var=tq*(1.f/256.f)-mu*mu;
      float rstd=1.f/sqrtf(var+1e-5f);
      const int c = t & 127, half = t >> 7;
      float acc = 0.f;
      if (c < 125){
        const int e0 = half*128;
#pragma unroll 8
        for (int e=e0; e<e0+128; e++) acc += outn[e]*swl[e*128+c];
      }
      if (half==1 && c<125) pp[c]=acc;
      __syncthreads();
      ull key=0ull;
      if (half==0 && c<125){
        int v=g*125+c;
        float a2 = rstd*(acc + pp[c] - mu*S1s[c]) + CONSTs[c];
        unsigned int fb=__float_as_uint(a2);
        fb = (fb&0x80000000u)? ~fb : (fb|0x80000000u);
        key=(((ull)fb)<<32) | (ull)(~(unsigned int)v);
      }
#pragma unroll
      for (int m=32;m;m>>=1){
        ull o=shflx64(key,m);
        key = (o>key)? o : key;
      }
      if (lane==0) redU[wid]=key;
      __syncthreads();
      if (t==0){
        ull kk=redU[0];
        if (redU[1]>kk) kk=redU[1];
        if (redU[2]>kk) kk=redU[2];
        if (redU[3]>kk) kk=redU[3];
        st_u64(KEY + g*8, kk);       // private line; no contention
      }
    }
    // ---- winner-barrier (worker side): arrive; poll own payload line ----
    {
      ++ep;
      __syncthreads();   // drains KEY store + all sc1 stage stores
      if (t==0){
        st_fi(ARR + g*16, ep);
        int r;
        while (((r = ld_fi(RELV2 + g*16)) >> 14) != ep) __builtin_amdgcn_s_sleep(1);
        winS = r & 0x3fff;
      }
      __syncthreads();
    }
  }

  // epilogue: final winner (broadcast by the last winner-barrier)
  if (g==0 && t==0) out[63] = winS;
}

extern "C" void kernel_launch(void* const* d_in, const int* in_sizes, int n_in,
                              void* d_out, int out_size, void* d_ws, size_t ws_size,
                              hipStream_t stream)
{
  (void)in_sizes; (void)n_in; (void)out_size; (void)ws_size;
  hipLaunchKernelGGL(gen18124_kernel, dim3(NWG), dim3(NT), 131072, stream,
    (const float*)d_in[0],  (const float*)d_in[1],  (const float*)d_in[2],
    (const float*)d_in[3],  (const float*)d_in[4],  (const float*)d_in[5],
    (const float*)d_in[6],  (const float*)d_in[7],  (const float*)d_in[8],
    (const float*)d_in[9],  (const float*)d_in[10], (const float*)d_in[11],
    (const float*)d_in[12], (const float*)d_in[13], (const float*)d_in[14],
    (const float*)d_in[15], (int*)d_out, (float*)d_ws);
}